// Round 13
// baseline (754.223 us; speedup 1.0000x reference)
//
#include <hip/hip_runtime.h>

#define N_PTS   100000
#define M_CL    12500
#define E0_N    1600000
#define E1_N    400000

#define NB      256
#define BIN_CAP 32
#define RANGE0  391
#define RANGE1  49
#define BCAP0   8192
#define BCAP1   2048

#define LSTR    72           // LDS row stride (shorts): 144 B, 16-B aligned

typedef unsigned short ushortT;
typedef short  short8 __attribute__((ext_vector_type(8)));
typedef float  v4f    __attribute__((ext_vector_type(4)));
typedef _Float16 h2   __attribute__((ext_vector_type(2)));
typedef unsigned u4v  __attribute__((ext_vector_type(4)));

__device__ inline ushortT f2bf(float x){
  union{float f; unsigned u;} v; v.f = x;
  unsigned r = v.u + 0x7fffu + ((v.u >> 16) & 1u);   // RNE
  return (ushortT)(r >> 16);
}
__device__ inline float bf2f(ushortT h){
  union{unsigned u; float f;} v; v.u = ((unsigned)h) << 16;
  return v.f;
}
__device__ inline ushortT f2h(float x){
  union{_Float16 h; ushortT u;} v; v.h = (_Float16)x;
  return v.u;
}
__device__ inline float h2f(ushortT u){
  union{ushortT u; _Float16 h;} v; v.u = u;
  return (float)v.h;
}
__device__ inline h2 pkmax(h2 a, h2 b){ return __builtin_elementwise_max(a, b); }
__device__ inline h2 u2h(unsigned u){ union{unsigned u; h2 h;} v{u}; return v.h; }

// ============================ bucketed CSR build ============================

__global__ void k_binit(int* c0, int* c1){
  int t = threadIdx.x;
  c0[t] = t*BCAP0;
  c1[t] = t*BCAP1;
}

template<int RANGE>
__global__ __launch_bounds__(256) void k_bin(const int* __restrict__ edges, int E,
                                             int* __restrict__ bcur, unsigned* __restrict__ tmp){
  __shared__ unsigned stage[NB*BIN_CAP];
  __shared__ int scnt[NB];
  __shared__ int sbase[NB];
  int tid = threadIdx.x;
  int nchunks = (E + 2047) / 2048;
  for (int c = blockIdx.x; c < nchunks; c += gridDim.x){
    int base = c*2048;
    scnt[tid] = 0;
    __syncthreads();
    #pragma unroll
    for (int r=0;r<8;++r){
      int e = base + r*256 + tid;
      if (e < E){
        int s = edges[2*e], d = edges[2*e+1];
        int bk = d / RANGE;
        unsigned packed = ((unsigned)s << 11) | (unsigned)(d - bk*RANGE);
        int pos = atomicAdd(&scnt[bk], 1);
        if (pos < BIN_CAP) stage[bk*BIN_CAP+pos] = packed;
        else tmp[atomicAdd(&bcur[bk],1)] = packed;
      }
    }
    __syncthreads();
    {
      int nfl = scnt[tid]; if (nfl > BIN_CAP) nfl = BIN_CAP;
      sbase[tid] = atomicAdd(&bcur[tid], nfl);
    }
    __syncthreads();
    int wv = tid >> 6, ln = tid & 63;
    for (int bb=0; bb<32; ++bb){
      int bk = wv*64 + bb*2 + (ln>>5);
      int ent = ln & 31;
      int nf = scnt[bk]; if (nf > BIN_CAP) nf = BIN_CAP;
      if (ent < nf) tmp[sbase[bk]+ent] = stage[bk*BIN_CAP+ent];
    }
    __syncthreads();
  }
}

__global__ void k_scan_bases(const int* c0, int* bb0, int* off0e,
                             const int* c1, int* bb1, int* off1e){
  const int* cur = blockIdx.x ? c1 : c0;
  int* bb = blockIdx.x ? bb1 : bb0;
  int* offe = blockIdx.x ? off1e : off0e;
  int BC = blockIdx.x ? BCAP1 : BCAP0;
  int lane = threadIdx.x & 63;
  int base = lane*4;
  int v0 = cur[base+0] - (base+0)*BC;
  int v1 = cur[base+1] - (base+1)*BC;
  int v2 = cur[base+2] - (base+2)*BC;
  int v3 = cur[base+3] - (base+3)*BC;
  int psum = v0+v1+v2+v3, sc = psum;
  #pragma unroll
  for (int st=1; st<64; st<<=1){
    int x = __shfl_up(sc, st, 64);
    if (lane >= st) sc += x;
  }
  int ex = sc - psum;
  bb[base+0] = ex;
  bb[base+1] = ex + v0;
  bb[base+2] = ex + v0 + v1;
  bb[base+3] = ex + v0 + v1 + v2;
  if (lane == 63) *offe = sc;
}

template<int RANGE, int BCAP>
__global__ __launch_bounds__(256) void k_csr_build(const unsigned* __restrict__ tmp, const int* __restrict__ bcur,
                                                   const int* __restrict__ bb, int n,
                                                   int* __restrict__ offs, int* __restrict__ csr){
  constexpr int K = (RANGE + 255) / 256;
  __shared__ int hist[RANGE];
  __shared__ int part[256];
  int b = blockIdx.x, tid = threadIdx.x;
  int dlo = b*RANGE;
  int range = n - dlo; if (range > RANGE) range = RANGE; if (range < 0) range = 0;
  int cnt = bcur[b] - b*BCAP;
  for (int t=tid; t<RANGE; t+=256) hist[t] = 0;
  __syncthreads();
  const unsigned* sl = tmp + (size_t)b*BCAP;
  for (int j=tid; j<cnt; j+=256) atomicAdd(&hist[sl[j] & 2047u], 1);
  __syncthreads();
  int s = 0; int loc[K];
  #pragma unroll
  for (int kk=0; kk<K; ++kk){
    int idx = tid*K + kk;
    int v = (idx < RANGE) ? hist[idx] : 0;
    loc[kk] = s; s += v;
  }
  part[tid] = s; __syncthreads();
  int own = s;
  for (int st=1; st<256; st<<=1){
    int x = (tid >= st) ? part[tid-st] : 0;
    __syncthreads();
    part[tid] += x;
    __syncthreads();
  }
  int ebase = part[tid] - own;
  int gb = bb[b];
  __syncthreads();
  #pragma unroll
  for (int kk=0; kk<K; ++kk){
    int idx = tid*K + kk;
    if (idx < RANGE){
      int ex = ebase + loc[kk];
      if (idx < range) offs[dlo+idx] = gb + ex;
      hist[idx] = ex;
    }
  }
  __syncthreads();
  for (int j=tid; j<cnt; j+=256){
    unsigned p = sl[j];
    int pos = atomicAdd(&hist[p & 2047u], 1);
    csr[gb + pos] = (int)(p >> 11);
  }
}

// ============================ label CSR ============================

__global__ __launch_bounds__(256) void k_count_lab(const int* __restrict__ labels, int n, int* __restrict__ cnt){
  int i = blockIdx.x*256 + threadIdx.x;
  if (i < n) atomicAdd(&cnt[labels[i]], 1);
}

__global__ __launch_bounds__(256) void k_chunk_sum(const int* __restrict__ cnt, int n, int* __restrict__ part){
  __shared__ int sd[256];
  int t = threadIdx.x, base = blockIdx.x*2048;
  int s = 0;
  #pragma unroll
  for (int r=0;r<8;++r){ int i = base + t*8 + r; if (i<n) s += cnt[i]; }
  sd[t]=s; __syncthreads();
  for (int st=128; st>0; st>>=1){ if (t<st) sd[t]+=sd[t+st]; __syncthreads(); }
  if (t==0) part[blockIdx.x]=sd[0];
}

__global__ void k_scan_part(int* part, int B, int* offs, int n){
  int lane = threadIdx.x & 63;
  int v = (lane < B) ? part[lane] : 0;
  int orig = v;
  #pragma unroll
  for (int st=1; st<64; st<<=1){
    int x = __shfl_up(v, st, 64);
    if (lane >= st) v += x;
  }
  if (lane < B) part[lane] = v - orig;
  if (lane == 63) offs[n] = v;
}

__global__ __launch_bounds__(256) void k_chunk_scan(const int* __restrict__ cnt, int n,
                                                    const int* __restrict__ part, int* __restrict__ offs){
  __shared__ int sd[256];
  int t=threadIdx.x, base=blockIdx.x*2048;
  int v[8]; int s=0;
  #pragma unroll
  for (int r=0;r<8;++r){ int i=base+t*8+r; v[r] = (i<n)?cnt[i]:0; s+=v[r]; }
  sd[t]=s; __syncthreads();
  for (int st=1; st<256; st<<=1){
    int x = (t>=st)? sd[t-st] : 0;
    __syncthreads();
    sd[t]+=x;
    __syncthreads();
  }
  int acc = part[blockIdx.x] + sd[t] - s;
  #pragma unroll
  for (int r=0;r<8;++r){ int i=base+t*8+r; if (i<n) offs[i]=acc; acc+=v[r]; }
}

__global__ __launch_bounds__(256) void k_fill_lab(const int* __restrict__ labels, int n,
                                                  const int* __restrict__ offs, int* __restrict__ cur,
                                                  int* __restrict__ csr){
  int i = blockIdx.x*256 + threadIdx.x;
  if (i < n){
    int d = labels[i];
    int p = atomicAdd(&cur[d], 1);
    csr[offs[d]+p] = i;
  }
}

// ============================ weight prep ============================

struct WSrc { const float* p[16]; };

__global__ __launch_bounds__(256) void k_wprep(WSrc s, ushortT* __restrict__ wt, ushortT* __restrict__ wtc){
  int slot = blockIdx.x;
  if (slot < 15){
    const float* src = s.p[slot];
    ushortT* dst = wt + slot*4096;
    for (int e=threadIdx.x; e<4096; e+=256){
      int nn = e>>6, kk = e&63;
      dst[e] = f2bf(src[kk*64+nn]);
    }
  } else {
    const float* src = s.p[15];
    for (int e=threadIdx.x; e<1024; e+=256){
      int nn = e>>6, kk = e&63;
      wtc[e] = (nn<8) ? f2bf(src[kk*8+nn]) : (ushortT)0;
    }
  }
}

// ============================ fused encoder: rel + f1(bf16) + g0'(f16 via MFMA) ============================

__global__ __launch_bounds__(256) void k_f1g(const float* __restrict__ features, const float* __restrict__ points,
                                             const float* __restrict__ centers, const int* __restrict__ labels,
                                             const float* __restrict__ W, const float* __restrict__ b,
                                             const ushortT* __restrict__ Wt2, const float* __restrict__ bias2,
                                             const float* __restrict__ Wr2,
                                             float* __restrict__ rel, ushortT* __restrict__ f1b,
                                             ushortT* __restrict__ gout, int n, int ntiles){
  __shared__ ushortT lds[4*16*LSTR];
  int tid = threadIdx.x;
  int lane = tid & 63, wslot = tid >> 6;
  int quad = lane >> 4, l15 = lane & 15;
  int gw = (blockIdx.x*256 + tid) >> 6;
  int nw = (gridDim.x*256) >> 6;
  float Wf0=W[0*64+lane], Wf1=W[1*64+lane], Wf2=W[2*64+lane], Wf3=W[3*64+lane];
  float wr0=W[4*64+lane], wr1=W[5*64+lane], wr2=W[6*64+lane];
  float bias=b[lane];
  short8 s0_0 = *(const short8*)(Wt2 + ( 0 + l15)*64 +  0 + quad*8);
  short8 s0_1 = *(const short8*)(Wt2 + ( 0 + l15)*64 + 32 + quad*8);
  short8 s1_0 = *(const short8*)(Wt2 + (16 + l15)*64 +  0 + quad*8);
  short8 s1_1 = *(const short8*)(Wt2 + (16 + l15)*64 + 32 + quad*8);
  short8 s2_0 = *(const short8*)(Wt2 + (32 + l15)*64 +  0 + quad*8);
  short8 s2_1 = *(const short8*)(Wt2 + (32 + l15)*64 + 32 + quad*8);
  short8 s3_0 = *(const short8*)(Wt2 + (48 + l15)*64 +  0 + quad*8);
  short8 s3_1 = *(const short8*)(Wt2 + (48 + l15)*64 + 32 + quad*8);
  float eb0 = bias2[l15], eb1 = bias2[16+l15], eb2 = bias2[32+l15], eb3 = bias2[48+l15];
  float e0c0=Wr2[0*64+l15], e0c1=Wr2[0*64+16+l15], e0c2=Wr2[0*64+32+l15], e0c3=Wr2[0*64+48+l15];
  float e1c0=Wr2[1*64+l15], e1c1=Wr2[1*64+16+l15], e1c2=Wr2[1*64+32+l15], e1c3=Wr2[1*64+48+l15];
  float e2c0=Wr2[2*64+l15], e2c1=Wr2[2*64+16+l15], e2c2=Wr2[2*64+32+l15], e2c3=Wr2[2*64+48+l15];

  for (int t=gw; t<ntiles; t+=nw){
    int i0 = t*16;
    for (int r=0;r<16;++r){
      int row = i0 + r;
      bool ok = row < n;
      int rr = ok ? row : n-1;
      int lb = labels[rr];
      float rx = points[rr*3+0]-centers[lb*3+0];
      float ry = points[rr*3+1]-centers[lb*3+1];
      float rz = points[rr*3+2]-centers[lb*3+2];
      float acc = bias + wr0*rx + wr1*ry + wr2*rz;
      acc += features[rr*4+0]*Wf0 + features[rr*4+1]*Wf1;
      acc += features[rr*4+2]*Wf2 + features[rr*4+3]*Wf3;
      acc = fmaxf(acc, 0.f);
      ushortT ab = f2bf(acc);
      if (ok){
        f1b[(size_t)row*64+lane] = ab;
        if (lane==0){ rel[row*3+0]=rx; rel[row*3+1]=ry; rel[row*3+2]=rz; }
      }
      lds[wslot*(16*LSTR) + r*LSTR + lane] = ab;
    }
    __builtin_amdgcn_wave_barrier();
    const ushortT* lp = lds + wslot*(16*LSTR) + l15*LSTR + quad*8;
    short8 sa0 = *(const short8*)(lp);
    short8 sa1 = *(const short8*)(lp + 32);
    __builtin_amdgcn_wave_barrier();
    v4f ec0 = {0.f,0.f,0.f,0.f}, ec1 = ec0, ec2 = ec0, ec3 = ec0;
    ec0 = __builtin_amdgcn_mfma_f32_16x16x32_bf16(sa0, s0_0, ec0, 0,0,0);
    ec1 = __builtin_amdgcn_mfma_f32_16x16x32_bf16(sa0, s1_0, ec1, 0,0,0);
    ec2 = __builtin_amdgcn_mfma_f32_16x16x32_bf16(sa0, s2_0, ec2, 0,0,0);
    ec3 = __builtin_amdgcn_mfma_f32_16x16x32_bf16(sa0, s3_0, ec3, 0,0,0);
    ec0 = __builtin_amdgcn_mfma_f32_16x16x32_bf16(sa1, s0_1, ec0, 0,0,0);
    ec1 = __builtin_amdgcn_mfma_f32_16x16x32_bf16(sa1, s1_1, ec1, 0,0,0);
    ec2 = __builtin_amdgcn_mfma_f32_16x16x32_bf16(sa1, s2_1, ec2, 0,0,0);
    ec3 = __builtin_amdgcn_mfma_f32_16x16x32_bf16(sa1, s3_1, ec3, 0,0,0);
    #pragma unroll
    for (int r=0;r<4;++r){
      int row = i0 + quad*4 + r;
      if (row < n){
        float vx=points[row*3+0], vy=points[row*3+1], vz=points[row*3+2];
        float g0 = ec0[r] + eb0 + vx*e0c0 + vy*e1c0 + vz*e2c0;
        float g1 = ec1[r] + eb1 + vx*e0c1 + vy*e1c1 + vz*e2c1;
        float g2 = ec2[r] + eb2 + vx*e0c2 + vy*e1c2 + vz*e2c2;
        float g3 = ec3[r] + eb3 + vx*e0c3 + vy*e1c3 + vz*e2c3;
        size_t base = (size_t)row*64 + l15;
        gout[base] = f2h(g0); gout[base+16] = f2h(g1); gout[base+32] = f2h(g2); gout[base+48] = f2h(g3);
      }
    }
  }
}

// ============================ MFMA GEMM; optional fused edge-agg input; optional fused secondary ============================
// AGGIN: A-tile comes from segment-max aggregation (8 lanes/dst, gathered from f16 aG rows),
//        written straight into the LDS relayout buffer — no global abuf round-trip.
// EMODE=1: secondary GEMM -> f16 eout; EMODE=2: classifier -> fp32 out[n x 8].

template<bool RELU, int NRES, bool USEREL, bool GATHER, bool OUT16, bool F16O, int EMODE, bool ERELU, bool AGGIN>
__global__ __launch_bounds__(256) void k_gemm(
    const ushortT* __restrict__ A, const ushortT* __restrict__ Wt,
    const float* __restrict__ bias, const float* __restrict__ Wr,
    const float* __restrict__ rel, const int* __restrict__ gidx,
    const ushortT* __restrict__ r1, const ushortT* __restrict__ r2,
    ushortT* __restrict__ out16,
    const ushortT* __restrict__ Wt2, const float* __restrict__ bias2,
    const float* __restrict__ Wr2, const float* __restrict__ vec2,
    void* __restrict__ eout,
    const int* __restrict__ aoffs, const int* __restrict__ acsr,
    const float* __restrict__ apos, const float* __restrict__ aWp,
    const ushortT* __restrict__ aG,
    int n, int ntiles)
{
  constexpr int LDSZ = (EMODE>0 || AGGIN) ? 4*16*LSTR : 4;
  __shared__ ushortT lds[LDSZ];
  int tid = threadIdx.x;
  int lane = tid & 63, wslot = tid >> 6;
  int quad = lane >> 4, l15 = lane & 15;
  int gw = (blockIdx.x*256 + tid) >> 6;
  int nw = (gridDim.x*256) >> 6;

  short8 bfr0_0 = *(const short8*)(Wt + ( 0 + l15)*64 +  0 + quad*8);
  short8 bfr0_1 = *(const short8*)(Wt + ( 0 + l15)*64 + 32 + quad*8);
  short8 bfr1_0 = *(const short8*)(Wt + (16 + l15)*64 +  0 + quad*8);
  short8 bfr1_1 = *(const short8*)(Wt + (16 + l15)*64 + 32 + quad*8);
  short8 bfr2_0 = *(const short8*)(Wt + (32 + l15)*64 +  0 + quad*8);
  short8 bfr2_1 = *(const short8*)(Wt + (32 + l15)*64 + 32 + quad*8);
  short8 bfr3_0 = *(const short8*)(Wt + (48 + l15)*64 +  0 + quad*8);
  short8 bfr3_1 = *(const short8*)(Wt + (48 + l15)*64 + 32 + quad*8);
  float bs0 = bias[ 0 + l15], bs1 = bias[16 + l15];
  float bs2 = bias[32 + l15], bs3 = bias[48 + l15];
  float w0c0=0,w0c1=0,w0c2=0,w0c3=0, w1c0=0,w1c1=0,w1c2=0,w1c3=0, w2c0=0,w2c1=0,w2c2=0,w2c3=0;
  if (USEREL){
    w0c0=Wr[0*64+l15]; w0c1=Wr[0*64+16+l15]; w0c2=Wr[0*64+32+l15]; w0c3=Wr[0*64+48+l15];
    w1c0=Wr[1*64+l15]; w1c1=Wr[1*64+16+l15]; w1c2=Wr[1*64+32+l15]; w1c3=Wr[1*64+48+l15];
    w2c0=Wr[2*64+l15]; w2c1=Wr[2*64+16+l15]; w2c2=Wr[2*64+32+l15]; w2c3=Wr[2*64+48+l15];
  }

  // agg lane mapping + pos-weights
  int grp = lane >> 3, d8 = lane & 7, gbase = lane & 56;
  const u4v* g4 = (const u4v*)aG;
  float2 aw0[4], aw1[4], aw2[4];
  if (AGGIN){
    #pragma unroll
    for (int q=0;q<4;++q){
      aw0[q] = *(const float2*)(aWp + 0*64 + d8*8 + 2*q);
      aw1[q] = *(const float2*)(aWp + 1*64 + d8*8 + 2*q);
      aw2[q] = *(const float2*)(aWp + 2*64 + d8*8 + 2*q);
    }
  }
  const h2 NEGBIG = {(_Float16)-60000.f, (_Float16)-60000.f};

  short8 s0_0{}, s0_1{}, s1_0{}, s1_1{}, s2_0{}, s2_1{}, s3_0{}, s3_1{};
  float eb0=0, eb1=0, eb2=0, eb3=0;
  float e0c0=0,e0c1=0,e0c2=0,e0c3=0, e1c0=0,e1c1=0,e1c2=0,e1c3=0, e2c0=0,e2c1=0,e2c2=0,e2c3=0;
  float ebias_c = 0.f;
  if (EMODE == 1){
    s0_0 = *(const short8*)(Wt2 + ( 0 + l15)*64 +  0 + quad*8);
    s0_1 = *(const short8*)(Wt2 + ( 0 + l15)*64 + 32 + quad*8);
    s1_0 = *(const short8*)(Wt2 + (16 + l15)*64 +  0 + quad*8);
    s1_1 = *(const short8*)(Wt2 + (16 + l15)*64 + 32 + quad*8);
    s2_0 = *(const short8*)(Wt2 + (32 + l15)*64 +  0 + quad*8);
    s2_1 = *(const short8*)(Wt2 + (32 + l15)*64 + 32 + quad*8);
    s3_0 = *(const short8*)(Wt2 + (48 + l15)*64 +  0 + quad*8);
    s3_1 = *(const short8*)(Wt2 + (48 + l15)*64 + 32 + quad*8);
    eb0 = bias2[l15]; eb1 = bias2[16+l15]; eb2 = bias2[32+l15]; eb3 = bias2[48+l15];
    e0c0=Wr2[0*64+l15]; e0c1=Wr2[0*64+16+l15]; e0c2=Wr2[0*64+32+l15]; e0c3=Wr2[0*64+48+l15];
    e1c0=Wr2[1*64+l15]; e1c1=Wr2[1*64+16+l15]; e1c2=Wr2[1*64+32+l15]; e1c3=Wr2[1*64+48+l15];
    e2c0=Wr2[2*64+l15]; e2c1=Wr2[2*64+16+l15]; e2c2=Wr2[2*64+32+l15]; e2c3=Wr2[2*64+48+l15];
  } else if (EMODE == 2){
    s0_0 = *(const short8*)(Wt2 + l15*64 +  0 + quad*8);
    s0_1 = *(const short8*)(Wt2 + l15*64 + 32 + quad*8);
    ebias_c = (l15 < 8) ? bias2[l15] : 0.f;
  }

  for (int t=gw; t<ntiles; t+=nw){
    int i0 = t*16;
    short8 a0, a1;
    if (AGGIN){
      #pragma unroll
      for (int p=0;p<2;++p){
        int ig = i0 + p*8 + grp;
        int igc = (ig < n) ? ig : n-1;
        int b = aoffs[igc], e = aoffs[igc+1];
        int cnt = e - b, c1 = cnt - 1;
        int mx = cnt;
        mx = max(mx, __shfl_xor(mx, 8, 64));
        mx = max(mx, __shfl_xor(mx, 16, 64));
        mx = max(mx, __shfl_xor(mx, 32, 64));
        h2 m0=NEGBIG, m1=NEGBIG, m2=NEGBIG, m3=NEGBIG;
        for (int J=0; J<mx; J+=8){
          if (J < cnt){
            int sv = acsr[b + min(J + d8, c1)];
            #pragma unroll
            for (int jj=0; jj<8; ++jj){
              int s = __shfl(sv, gbase + jj, 64);
              u4v u = g4[(size_t)s*8 + d8];
              m0 = pkmax(m0, u2h(u.x));
              m1 = pkmax(m1, u2h(u.y));
              m2 = pkmax(m2, u2h(u.z));
              m3 = pkmax(m3, u2h(u.w));
            }
          }
        }
        float px = apos[igc*3+0], py = apos[igc*3+1], pz = apos[igc*3+2];
        u4v outv;
        {
          float sA = aw0[0].x*px + aw1[0].x*py + aw2[0].x*pz;
          float sB = aw0[0].y*px + aw1[0].y*py + aw2[0].y*pz;
          outv.x = (unsigned)f2bf(fmaxf((float)m0.x - sA, 0.f)) |
                   ((unsigned)f2bf(fmaxf((float)m0.y - sB, 0.f)) << 16);
        }
        {
          float sA = aw0[1].x*px + aw1[1].x*py + aw2[1].x*pz;
          float sB = aw0[1].y*px + aw1[1].y*py + aw2[1].y*pz;
          outv.y = (unsigned)f2bf(fmaxf((float)m1.x - sA, 0.f)) |
                   ((unsigned)f2bf(fmaxf((float)m1.y - sB, 0.f)) << 16);
        }
        {
          float sA = aw0[2].x*px + aw1[2].x*py + aw2[2].x*pz;
          float sB = aw0[2].y*px + aw1[2].y*py + aw2[2].y*pz;
          outv.z = (unsigned)f2bf(fmaxf((float)m2.x - sA, 0.f)) |
                   ((unsigned)f2bf(fmaxf((float)m2.y - sB, 0.f)) << 16);
        }
        {
          float sA = aw0[3].x*px + aw1[3].x*py + aw2[3].x*pz;
          float sB = aw0[3].y*px + aw1[3].y*py + aw2[3].y*pz;
          outv.w = (unsigned)f2bf(fmaxf((float)m3.x - sA, 0.f)) |
                   ((unsigned)f2bf(fmaxf((float)m3.y - sB, 0.f)) << 16);
        }
        *(u4v*)(lds + wslot*(16*LSTR) + (p*8+grp)*LSTR + d8*8) = outv;
      }
      __builtin_amdgcn_wave_barrier();
      const ushortT* lpa = lds + wslot*(16*LSTR) + l15*LSTR + quad*8;
      a0 = *(const short8*)(lpa);
      a1 = *(const short8*)(lpa + 32);
      __builtin_amdgcn_wave_barrier();
    } else {
      int rowA = i0 + l15; if (rowA >= n) rowA = n-1;
      if (GATHER) rowA = gidx[rowA];
      const ushortT* ap = A + (size_t)rowA*64 + quad*8;
      a0 = *(const short8*)(ap);
      a1 = *(const short8*)(ap + 32);
    }
    v4f ac0 = {0.f,0.f,0.f,0.f}, ac1 = ac0, ac2 = ac0, ac3 = ac0;
    ac0 = __builtin_amdgcn_mfma_f32_16x16x32_bf16(a0, bfr0_0, ac0, 0,0,0);
    ac1 = __builtin_amdgcn_mfma_f32_16x16x32_bf16(a0, bfr1_0, ac1, 0,0,0);
    ac2 = __builtin_amdgcn_mfma_f32_16x16x32_bf16(a0, bfr2_0, ac2, 0,0,0);
    ac3 = __builtin_amdgcn_mfma_f32_16x16x32_bf16(a0, bfr3_0, ac3, 0,0,0);
    ac0 = __builtin_amdgcn_mfma_f32_16x16x32_bf16(a1, bfr0_1, ac0, 0,0,0);
    ac1 = __builtin_amdgcn_mfma_f32_16x16x32_bf16(a1, bfr1_1, ac1, 0,0,0);
    ac2 = __builtin_amdgcn_mfma_f32_16x16x32_bf16(a1, bfr2_1, ac2, 0,0,0);
    ac3 = __builtin_amdgcn_mfma_f32_16x16x32_bf16(a1, bfr3_1, ac3, 0,0,0);

    #pragma unroll
    for (int r=0;r<4;++r){
      int row = i0 + quad*4 + r;
      bool rowok = (row < n);
      float rx=0.f, ry=0.f, rz=0.f;
      if (USEREL && rowok){ rx=rel[row*3+0]; ry=rel[row*3+1]; rz=rel[row*3+2]; }
      float v0 = ac0[r] + bs0, v1 = ac1[r] + bs1, v2 = ac2[r] + bs2, v3 = ac3[r] + bs3;
      if (USEREL){
        v0 += rx*w0c0 + ry*w1c0 + rz*w2c0;
        v1 += rx*w0c1 + ry*w1c1 + rz*w2c1;
        v2 += rx*w0c2 + ry*w1c2 + rz*w2c2;
        v3 += rx*w0c3 + ry*w1c3 + rz*w2c3;
      }
      if (RELU){ v0=fmaxf(v0,0.f); v1=fmaxf(v1,0.f); v2=fmaxf(v2,0.f); v3=fmaxf(v3,0.f); }
      size_t base = (size_t)row*64 + l15;
      if (rowok){
        if (NRES>=1){
          v0 += bf2f(r1[base]); v1 += bf2f(r1[base+16]); v2 += bf2f(r1[base+32]); v3 += bf2f(r1[base+48]);
        }
        if (NRES>=2){
          v0 += bf2f(r2[base]); v1 += bf2f(r2[base+16]); v2 += bf2f(r2[base+32]); v3 += bf2f(r2[base+48]);
        }
        if (OUT16){
          if (F16O){
            out16[base] = f2h(v0); out16[base+16] = f2h(v1); out16[base+32] = f2h(v2); out16[base+48] = f2h(v3);
          } else {
            out16[base] = f2bf(v0); out16[base+16] = f2bf(v1); out16[base+32] = f2bf(v2); out16[base+48] = f2bf(v3);
          }
        }
      }
      if (EMODE > 0){
        int lb = wslot*(16*LSTR) + (quad*4+r)*LSTR + l15;
        lds[lb]      = f2bf(v0);
        lds[lb + 16] = f2bf(v1);
        lds[lb + 32] = f2bf(v2);
        lds[lb + 48] = f2bf(v3);
      }
    }

    if (EMODE > 0){
      __builtin_amdgcn_wave_barrier();
      const ushortT* lp = lds + wslot*(16*LSTR) + l15*LSTR + quad*8;
      short8 sa0 = *(const short8*)(lp);
      short8 sa1 = *(const short8*)(lp + 32);
      __builtin_amdgcn_wave_barrier();
      if (EMODE == 1){
        v4f ec0 = {0.f,0.f,0.f,0.f}, ec1 = ec0, ec2 = ec0, ec3 = ec0;
        ec0 = __builtin_amdgcn_mfma_f32_16x16x32_bf16(sa0, s0_0, ec0, 0,0,0);
        ec1 = __builtin_amdgcn_mfma_f32_16x16x32_bf16(sa0, s1_0, ec1, 0,0,0);
        ec2 = __builtin_amdgcn_mfma_f32_16x16x32_bf16(sa0, s2_0, ec2, 0,0,0);
        ec3 = __builtin_amdgcn_mfma_f32_16x16x32_bf16(sa0, s3_0, ec3, 0,0,0);
        ec0 = __builtin_amdgcn_mfma_f32_16x16x32_bf16(sa1, s0_1, ec0, 0,0,0);
        ec1 = __builtin_amdgcn_mfma_f32_16x16x32_bf16(sa1, s1_1, ec1, 0,0,0);
        ec2 = __builtin_amdgcn_mfma_f32_16x16x32_bf16(sa1, s2_1, ec2, 0,0,0);
        ec3 = __builtin_amdgcn_mfma_f32_16x16x32_bf16(sa1, s3_1, ec3, 0,0,0);
        ushortT* eo = (ushortT*)eout;
        #pragma unroll
        for (int r=0;r<4;++r){
          int row = i0 + quad*4 + r;
          if (row < n){
            float vx=vec2[row*3+0], vy=vec2[row*3+1], vz=vec2[row*3+2];
            float g0 = ec0[r] + eb0 + vx*e0c0 + vy*e1c0 + vz*e2c0;
            float g1 = ec1[r] + eb1 + vx*e0c1 + vy*e1c1 + vz*e2c1;
            float g2 = ec2[r] + eb2 + vx*e0c2 + vy*e1c2 + vz*e2c2;
            float g3 = ec3[r] + eb3 + vx*e0c3 + vy*e1c3 + vz*e2c3;
            if (ERELU){ g0=fmaxf(g0,0.f); g1=fmaxf(g1,0.f); g2=fmaxf(g2,0.f); g3=fmaxf(g3,0.f); }
            size_t base = (size_t)row*64 + l15;
            eo[base] = f2h(g0); eo[base+16] = f2h(g1); eo[base+32] = f2h(g2); eo[base+48] = f2h(g3);
          }
        }
      } else {
        v4f ec = {0.f,0.f,0.f,0.f};
        ec = __builtin_amdgcn_mfma_f32_16x16x32_bf16(sa0, s0_0, ec, 0,0,0);
        ec = __builtin_amdgcn_mfma_f32_16x16x32_bf16(sa1, s0_1, ec, 0,0,0);
        if (l15 < 8){
          float* eo = (float*)eout;
          #pragma unroll
          for (int r=0;r<4;++r){
            int row = i0 + quad*4 + r;
            if (row < n) eo[(size_t)row*8 + l15] = ec[r] + ebias_c;
          }
        }
      }
    }
  }
}

// ============================ segment sum via label CSR (f16 in, bf16 out) ============================

__global__ __launch_bounds__(256) void k_seg_gather(const int* __restrict__ offs, const int* __restrict__ csr,
                                                    const ushortT* __restrict__ h, ushortT* __restrict__ c, int m){
  int lane = threadIdx.x & 63;
  int wv = (blockIdx.x*256 + threadIdx.x) >> 6;
  if (wv >= m) return;
  int b = offs[wv], e = offs[wv+1];
  float acc = 0.f;
  for (int k=b; k<e; ++k){
    int i = csr[k];
    acc += h2f(h[(size_t)i*64+lane]);
  }
  c[(size_t)wv*64+lane] = f2bf(acc);
}

// ============================ host launcher ============================

extern "C" void kernel_launch(void* const* d_in, const int* in_sizes, int n_in,
                              void* d_out, int out_size, void* d_ws, size_t ws_size,
                              hipStream_t stream){
  const float* features = (const float*)d_in[0];
  const float* points   = (const float*)d_in[1];
  const float* centers  = (const float*)d_in[2];
  const int*   l0e      = (const int*)d_in[3];
  const int*   l1e      = (const int*)d_in[4];
  const int*   labels   = (const int*)d_in[5];
  const float* W_fe = (const float*)d_in[6];
  const float* b_fe = (const float*)d_in[7];
  const float* mWe  = (const float*)d_in[8];
  const float* mbe  = (const float*)d_in[9];
  const float* mWu  = (const float*)d_in[10];
  const float* mbu  = (const float*)d_in[11];
  const float* W_m1 = (const float*)d_in[12];
  const float* b_m1 = (const float*)d_in[13];
  const float* W_m2 = (const float*)d_in[14];
  const float* b_m2 = (const float*)d_in[15];
  const float* gWe  = (const float*)d_in[16];
  const float* gbe  = (const float*)d_in[17];
  const float* gWu  = (const float*)d_in[18];
  const float* gbu  = (const float*)d_in[19];
  const float* W_l  = (const float*)d_in[20];
  const float* b_l  = (const float*)d_in[21];
  const float* W_c  = (const float*)d_in[22];
  const float* b_c  = (const float*)d_in[23];
  float* out = (float*)d_out;

  char* w = (char*)d_ws;
  size_t off = 0;
  auto alloc = [&](size_t bytes)->void*{
    void* p = (void*)(w + off);
    off = (off + bytes + 255) & ~(size_t)255;
    return p;
  };
  float* rel  = (float*)alloc((size_t)N_PTS*3*4);
  ushortT* UF1 = (ushortT*)alloc((size_t)N_PTS*64*2);
  ushortT* UF2 = (ushortT*)alloc((size_t)N_PTS*64*2);
  ushortT* UF21= (ushortT*)alloc((size_t)N_PTS*64*2);
  ushortT* UF5 = (ushortT*)alloc((size_t)N_PTS*64*2);
  ushortT* UF6 = (ushortT*)alloc((size_t)N_PTS*64*2);
  ushortT* gA  = (ushortT*)alloc((size_t)N_PTS*64*2);   // f16 g'/h ping
  ushortT* gB  = (ushortT*)alloc((size_t)N_PTS*64*2);   // f16 g' pong
  ushortT* cb_b= (ushortT*)alloc((size_t)M_CL*64*2);
  ushortT* UF3 = (ushortT*)alloc((size_t)M_CL*64*2);
  ushortT* UF4 = (ushortT*)alloc((size_t)M_CL*64*2);
  ushortT* cgA = (ushortT*)alloc((size_t)M_CL*64*2);
  ushortT* cgB = (ushortT*)alloc((size_t)M_CL*64*2);
  ushortT* f41_b  = (ushortT*)alloc((size_t)M_CL*64*2);
  ushortT* wt  = (ushortT*)alloc((size_t)15*4096*2);
  ushortT* wtc = (ushortT*)alloc((size_t)1024*2);
  int* offs0 = (int*)alloc((size_t)(N_PTS+1)*4);
  int* csr0  = (int*)alloc((size_t)E0_N*4);
  int* offs1 = (int*)alloc((size_t)(M_CL+1)*4);
  int* csr1  = (int*)alloc((size_t)E1_N*4);
  unsigned* tmp0 = (unsigned*)alloc((size_t)NB*BCAP0*4);
  unsigned* tmp1 = (unsigned*)alloc((size_t)NB*BCAP1*4);
  int* bcur0 = (int*)alloc(NB*4);
  int* bcur1 = (int*)alloc(NB*4);
  int* bb0   = (int*)alloc(NB*4);
  int* bb1   = (int*)alloc(NB*4);
  char* zbase = (char*)alloc(0);
  int* cntL = (int*)alloc((size_t)M_CL*4);
  int* curL = (int*)alloc((size_t)M_CL*4);
  size_t zbytes = (size_t)((char*)(w+off) - zbase);
  int* offsL = (int*)alloc((size_t)(M_CL+1)*4);
  int* csrL  = (int*)alloc((size_t)N_PTS*4);
  int* partL = (int*)alloc(64*4);
  (void)ws_size; (void)in_sizes; (void)n_in; (void)out_size;

  const int NT_N = (N_PTS+15)/16;
  const int NT_M = (M_CL +15)/16;
  const int GBG_N = 1563;
  const int GBG_M = 196;

  hipMemsetAsync(zbase, 0, zbytes, stream);

  // ---- CSR builds (256 buckets) ----
  k_binit<<<1, 256, 0, stream>>>(bcur0, bcur1);
  k_bin<RANGE0><<<256, 256, 0, stream>>>(l0e, E0_N, bcur0, tmp0);
  k_bin<RANGE1><<<196, 256, 0, stream>>>(l1e, E1_N, bcur1, tmp1);
  k_scan_bases<<<2, 64, 0, stream>>>(bcur0, bb0, offs0+N_PTS, bcur1, bb1, offs1+M_CL);
  k_csr_build<RANGE0,BCAP0><<<NB, 256, 0, stream>>>(tmp0, bcur0, bb0, N_PTS, offs0, csr0);
  k_csr_build<RANGE1,BCAP1><<<NB, 256, 0, stream>>>(tmp1, bcur1, bb1, M_CL, offs1, csr1);

  // ---- label CSR ----
  k_count_lab<<<(N_PTS+255)/256, 256, 0, stream>>>(labels, N_PTS, cntL);
  k_chunk_sum<<<7, 256, 0, stream>>>(cntL, M_CL, partL);
  k_scan_part<<<1, 64, 0, stream>>>(partL, 7, offsL, M_CL);
  k_chunk_scan<<<7, 256, 0, stream>>>(cntL, M_CL, partL, offsL);
  k_fill_lab<<<(N_PTS+255)/256, 256, 0, stream>>>(labels, N_PTS, offsL, curL, csrL);

  // ---- weight prep ----
  WSrc ws{};
  ws.p[0]=mWu+0*4096; ws.p[1]=mWu+1*4096; ws.p[2]=mWu+2*4096; ws.p[3]=mWu+3*4096;
  ws.p[4]=W_m2; ws.p[5]=gWu+0*4096; ws.p[6]=gWu+1*4096;
  ws.p[7]=mWe+0*4288+192; ws.p[8]=mWe+1*4288+192; ws.p[9]=mWe+2*4288+192; ws.p[10]=mWe+3*4288+192;
  ws.p[11]=W_m1; ws.p[12]=W_l; ws.p[13]=gWe+0*4288+192; ws.p[14]=gWe+1*4288+192;
  ws.p[15]=W_c;
  k_wprep<<<16, 256, 0, stream>>>(ws, wt, wtc);

  // ---- FUSED encoder: rel + f1 (bf16) + g0' -> gA ----
  k_f1g<<<GBG_N, 256, 0, stream>>>(features, points, centers, labels, W_fe, b_fe,
      wt+7*4096, mbe+0, mWe+0*4288, rel, UF1, gA, N_PTS, NT_N);

  // ---- layer0: FUSED [agg(gA)] + [f2 -> UF2] + [g1' -> gB] ----
  k_gemm<true,1,false,false,true,false,1,false,true><<<GBG_N,256,0,stream>>>(nullptr, wt+0*4096, mbu+0,
      nullptr, nullptr, nullptr, UF1, nullptr, UF2,
      wt+8*4096, mbe+64, mWe+1*4288, points, gB,
      offs0, csr0, points, mWe+0*4288, gA, N_PTS, NT_N);
  // ---- layer1: FUSED [agg(gB)] + [f2_1 -> UF21] + [h -> gA] ----
  k_gemm<true,1,false,false,true,false,1,true,true><<<GBG_N,256,0,stream>>>(nullptr, wt+1*4096, mbu+64,
      nullptr, nullptr, nullptr, UF2, nullptr, UF21,
      wt+11*4096, b_m1, W_m1+4096, rel, gA,
      offs0, csr0, points, mWe+1*4288, gB, N_PTS, NT_N);
  // ---- c = segsum(h in gA); FUSED [f3 -> UF3] + [cg0' -> cgA] ----
  k_seg_gather<<<(M_CL*64+255)/256, 256, 0, stream>>>(offsL, csrL, gA, cb_b, M_CL);
  k_gemm<true,0,false,false,true,false,1,false,false><<<GBG_M,256,0,stream>>>(cb_b, wt+4*4096, b_m2,
      nullptr, nullptr, nullptr, nullptr, nullptr, UF3,
      wt+13*4096, gbe+0, gWe+0*4288, centers, cgA,
      nullptr, nullptr, nullptr, nullptr, nullptr, M_CL, NT_M);
  // ---- cluster layer0: FUSED [agg(cgA)] + [f4 -> UF4] + [cg1' -> cgB] ----
  k_gemm<true,1,false,false,true,false,1,false,true><<<GBG_M,256,0,stream>>>(nullptr, wt+5*4096, gbu+0,
      nullptr, nullptr, nullptr, UF3, nullptr, UF4,
      wt+14*4096, gbe+64, gWe+1*4288, centers, cgB,
      offs1, csr1, centers, gWe+0*4288, cgA, M_CL, NT_M);
  // ---- cluster layer1: FUSED [agg(cgB)] + [f4_1 -> f41_b] ----
  k_gemm<true,1,false,false,true,false,0,false,true><<<GBG_M,256,0,stream>>>(nullptr, wt+6*4096, gbu+64,
      nullptr, nullptr, nullptr, UF4, nullptr, f41_b,
      nullptr, nullptr, nullptr, nullptr, nullptr,
      offs1, csr1, centers, gWe+1*4288, cgB, M_CL, NT_M);
  // ---- FUSED [f5 -> UF5] + [g2' -> gB] (gather from f41_b) ----
  k_gemm<true,0,true,true,true,false,1,false,false><<<GBG_N,256,0,stream>>>(f41_b, wt+12*4096, b_l,
      W_l+4096, rel, labels, nullptr, nullptr, UF5,
      wt+9*4096, mbe+128, mWe+2*4288, points, gB,
      nullptr, nullptr, nullptr, nullptr, nullptr, N_PTS, NT_N);
  // ---- layer2: FUSED [agg(gB)] + [f6 -> UF6] + [g3' -> gA] ----
  k_gemm<true,2,false,false,true,false,1,false,true><<<GBG_N,256,0,stream>>>(nullptr, wt+2*4096, mbu+128,
      nullptr, nullptr, nullptr, UF5, UF21, UF6,
      wt+10*4096, mbe+192, mWe+3*4288, points, gA,
      offs0, csr0, points, mWe+2*4288, gB, N_PTS, NT_N);
  // ---- layer3: FUSED [agg(gA)] + [final = relu+f6+f2] + [out = final@W_c + b_c] ----
  k_gemm<true,2,false,false,false,false,2,false,true><<<GBG_N,256,0,stream>>>(nullptr, wt+3*4096, mbu+192,
      nullptr, nullptr, nullptr, UF6, UF2, nullptr,
      wtc, b_c, nullptr, nullptr, out,
      offs0, csr0, points, mWe+3*4288, gA, N_PTS, NT_N);
}

// Round 14
// 525.419 us; speedup vs baseline: 1.4355x; 1.4355x over previous
//
#include <hip/hip_runtime.h>

#define N_PTS   100000
#define M_CL    12500
#define E0_N    1600000
#define E1_N    400000

#define NB      256
#define BIN_CAP 32
#define RANGE0  391
#define RANGE1  49
#define BCAP0   8192
#define BCAP1   2048

#define LSTR    72           // LDS row stride (shorts): 144 B, 16-B aligned

typedef unsigned short ushortT;
typedef short  short8 __attribute__((ext_vector_type(8)));
typedef float  v4f    __attribute__((ext_vector_type(4)));
typedef _Float16 h2   __attribute__((ext_vector_type(2)));
typedef unsigned u4v  __attribute__((ext_vector_type(4)));

__device__ inline ushortT f2bf(float x){
  union{float f; unsigned u;} v; v.f = x;
  unsigned r = v.u + 0x7fffu + ((v.u >> 16) & 1u);   // RNE
  return (ushortT)(r >> 16);
}
__device__ inline float bf2f(ushortT h){
  union{unsigned u; float f;} v; v.u = ((unsigned)h) << 16;
  return v.f;
}
__device__ inline ushortT f2h(float x){
  union{_Float16 h; ushortT u;} v; v.h = (_Float16)x;
  return v.u;
}
__device__ inline float h2f(ushortT u){
  union{ushortT u; _Float16 h;} v; v.u = u;
  return (float)v.h;
}
__device__ inline h2 pkmax(h2 a, h2 b){ return __builtin_elementwise_max(a, b); }
__device__ inline h2 u2h(unsigned u){ union{unsigned u; h2 h;} v{u}; return v.h; }

// ============================ bucketed CSR build ============================

__global__ void k_binit(int* c0, int* c1){
  int t = threadIdx.x;
  c0[t] = t*BCAP0;
  c1[t] = t*BCAP1;
}

template<int RANGE>
__global__ __launch_bounds__(256) void k_bin(const int* __restrict__ edges, int E,
                                             int* __restrict__ bcur, unsigned* __restrict__ tmp){
  __shared__ unsigned stage[NB*BIN_CAP];
  __shared__ int scnt[NB];
  __shared__ int sbase[NB];
  int tid = threadIdx.x;
  int nchunks = (E + 2047) / 2048;
  for (int c = blockIdx.x; c < nchunks; c += gridDim.x){
    int base = c*2048;
    scnt[tid] = 0;
    __syncthreads();
    #pragma unroll
    for (int r=0;r<8;++r){
      int e = base + r*256 + tid;
      if (e < E){
        int s = edges[2*e], d = edges[2*e+1];
        int bk = d / RANGE;
        unsigned packed = ((unsigned)s << 11) | (unsigned)(d - bk*RANGE);
        int pos = atomicAdd(&scnt[bk], 1);
        if (pos < BIN_CAP) stage[bk*BIN_CAP+pos] = packed;
        else tmp[atomicAdd(&bcur[bk],1)] = packed;
      }
    }
    __syncthreads();
    {
      int nfl = scnt[tid]; if (nfl > BIN_CAP) nfl = BIN_CAP;
      sbase[tid] = atomicAdd(&bcur[tid], nfl);
    }
    __syncthreads();
    int wv = tid >> 6, ln = tid & 63;
    for (int bb=0; bb<32; ++bb){
      int bk = wv*64 + bb*2 + (ln>>5);
      int ent = ln & 31;
      int nf = scnt[bk]; if (nf > BIN_CAP) nf = BIN_CAP;
      if (ent < nf) tmp[sbase[bk]+ent] = stage[bk*BIN_CAP+ent];
    }
    __syncthreads();
  }
}

__global__ void k_scan_bases(const int* c0, int* bb0, int* off0e,
                             const int* c1, int* bb1, int* off1e){
  const int* cur = blockIdx.x ? c1 : c0;
  int* bb = blockIdx.x ? bb1 : bb0;
  int* offe = blockIdx.x ? off1e : off0e;
  int BC = blockIdx.x ? BCAP1 : BCAP0;
  int lane = threadIdx.x & 63;
  int base = lane*4;
  int v0 = cur[base+0] - (base+0)*BC;
  int v1 = cur[base+1] - (base+1)*BC;
  int v2 = cur[base+2] - (base+2)*BC;
  int v3 = cur[base+3] - (base+3)*BC;
  int psum = v0+v1+v2+v3, sc = psum;
  #pragma unroll
  for (int st=1; st<64; st<<=1){
    int x = __shfl_up(sc, st, 64);
    if (lane >= st) sc += x;
  }
  int ex = sc - psum;
  bb[base+0] = ex;
  bb[base+1] = ex + v0;
  bb[base+2] = ex + v0 + v1;
  bb[base+3] = ex + v0 + v1 + v2;
  if (lane == 63) *offe = sc;
}

template<int RANGE, int BCAP>
__global__ __launch_bounds__(256) void k_csr_build(const unsigned* __restrict__ tmp, const int* __restrict__ bcur,
                                                   const int* __restrict__ bb, int n,
                                                   int* __restrict__ offs, int* __restrict__ csr){
  constexpr int K = (RANGE + 255) / 256;
  __shared__ int hist[RANGE];
  __shared__ int part[256];
  int b = blockIdx.x, tid = threadIdx.x;
  int dlo = b*RANGE;
  int range = n - dlo; if (range > RANGE) range = RANGE; if (range < 0) range = 0;
  int cnt = bcur[b] - b*BCAP;
  for (int t=tid; t<RANGE; t+=256) hist[t] = 0;
  __syncthreads();
  const unsigned* sl = tmp + (size_t)b*BCAP;
  for (int j=tid; j<cnt; j+=256) atomicAdd(&hist[sl[j] & 2047u], 1);
  __syncthreads();
  int s = 0; int loc[K];
  #pragma unroll
  for (int kk=0; kk<K; ++kk){
    int idx = tid*K + kk;
    int v = (idx < RANGE) ? hist[idx] : 0;
    loc[kk] = s; s += v;
  }
  part[tid] = s; __syncthreads();
  int own = s;
  for (int st=1; st<256; st<<=1){
    int x = (tid >= st) ? part[tid-st] : 0;
    __syncthreads();
    part[tid] += x;
    __syncthreads();
  }
  int ebase = part[tid] - own;
  int gb = bb[b];
  __syncthreads();
  #pragma unroll
  for (int kk=0; kk<K; ++kk){
    int idx = tid*K + kk;
    if (idx < RANGE){
      int ex = ebase + loc[kk];
      if (idx < range) offs[dlo+idx] = gb + ex;
      hist[idx] = ex;
    }
  }
  __syncthreads();
  for (int j=tid; j<cnt; j+=256){
    unsigned p = sl[j];
    int pos = atomicAdd(&hist[p & 2047u], 1);
    csr[gb + pos] = (int)(p >> 11);
  }
}

// ============================ label CSR ============================

__global__ __launch_bounds__(256) void k_count_lab(const int* __restrict__ labels, int n, int* __restrict__ cnt){
  int i = blockIdx.x*256 + threadIdx.x;
  if (i < n) atomicAdd(&cnt[labels[i]], 1);
}

__global__ __launch_bounds__(256) void k_chunk_sum(const int* __restrict__ cnt, int n, int* __restrict__ part){
  __shared__ int sd[256];
  int t = threadIdx.x, base = blockIdx.x*2048;
  int s = 0;
  #pragma unroll
  for (int r=0;r<8;++r){ int i = base + t*8 + r; if (i<n) s += cnt[i]; }
  sd[t]=s; __syncthreads();
  for (int st=128; st>0; st>>=1){ if (t<st) sd[t]+=sd[t+st]; __syncthreads(); }
  if (t==0) part[blockIdx.x]=sd[0];
}

__global__ void k_scan_part(int* part, int B, int* offs, int n){
  int lane = threadIdx.x & 63;
  int v = (lane < B) ? part[lane] : 0;
  int orig = v;
  #pragma unroll
  for (int st=1; st<64; st<<=1){
    int x = __shfl_up(v, st, 64);
    if (lane >= st) v += x;
  }
  if (lane < B) part[lane] = v - orig;
  if (lane == 63) offs[n] = v;
}

__global__ __launch_bounds__(256) void k_chunk_scan(const int* __restrict__ cnt, int n,
                                                    const int* __restrict__ part, int* __restrict__ offs){
  __shared__ int sd[256];
  int t=threadIdx.x, base=blockIdx.x*2048;
  int v[8]; int s=0;
  #pragma unroll
  for (int r=0;r<8;++r){ int i=base+t*8+r; v[r] = (i<n)?cnt[i]:0; s+=v[r]; }
  sd[t]=s; __syncthreads();
  for (int st=1; st<256; st<<=1){
    int x = (t>=st)? sd[t-st] : 0;
    __syncthreads();
    sd[t]+=x;
    __syncthreads();
  }
  int acc = part[blockIdx.x] + sd[t] - s;
  #pragma unroll
  for (int r=0;r<8;++r){ int i=base+t*8+r; if (i<n) offs[i]=acc; acc+=v[r]; }
}

__global__ __launch_bounds__(256) void k_fill_lab(const int* __restrict__ labels, int n,
                                                  const int* __restrict__ offs, int* __restrict__ cur,
                                                  int* __restrict__ csr){
  int i = blockIdx.x*256 + threadIdx.x;
  if (i < n){
    int d = labels[i];
    int p = atomicAdd(&cur[d], 1);
    csr[offs[d]+p] = i;
  }
}

// ============================ weight prep ============================

struct WSrc { const float* p[16]; };

__global__ __launch_bounds__(256) void k_wprep(WSrc s, ushortT* __restrict__ wt, ushortT* __restrict__ wtc){
  int slot = blockIdx.x;
  if (slot < 15){
    const float* src = s.p[slot];
    ushortT* dst = wt + slot*4096;
    for (int e=threadIdx.x; e<4096; e+=256){
      int nn = e>>6, kk = e&63;
      dst[e] = f2bf(src[kk*64+nn]);
    }
  } else {
    const float* src = s.p[15];
    for (int e=threadIdx.x; e<1024; e+=256){
      int nn = e>>6, kk = e&63;
      wtc[e] = (nn<8) ? f2bf(src[kk*8+nn]) : (ushortT)0;
    }
  }
}

// ============================ fused encoder: rel + f1(bf16) + g0'(f16 via MFMA) ============================

__global__ __launch_bounds__(256) void k_f1g(const float* __restrict__ features, const float* __restrict__ points,
                                             const float* __restrict__ centers, const int* __restrict__ labels,
                                             const float* __restrict__ W, const float* __restrict__ b,
                                             const ushortT* __restrict__ Wt2, const float* __restrict__ bias2,
                                             const float* __restrict__ Wr2,
                                             float* __restrict__ rel, ushortT* __restrict__ f1b,
                                             ushortT* __restrict__ gout, int n, int ntiles){
  __shared__ ushortT lds[4*16*LSTR];
  int tid = threadIdx.x;
  int lane = tid & 63, wslot = tid >> 6;
  int quad = lane >> 4, l15 = lane & 15;
  int gw = (blockIdx.x*256 + tid) >> 6;
  int nw = (gridDim.x*256) >> 6;
  float Wf0=W[0*64+lane], Wf1=W[1*64+lane], Wf2=W[2*64+lane], Wf3=W[3*64+lane];
  float wr0=W[4*64+lane], wr1=W[5*64+lane], wr2=W[6*64+lane];
  float bias=b[lane];
  short8 s0_0 = *(const short8*)(Wt2 + ( 0 + l15)*64 +  0 + quad*8);
  short8 s0_1 = *(const short8*)(Wt2 + ( 0 + l15)*64 + 32 + quad*8);
  short8 s1_0 = *(const short8*)(Wt2 + (16 + l15)*64 +  0 + quad*8);
  short8 s1_1 = *(const short8*)(Wt2 + (16 + l15)*64 + 32 + quad*8);
  short8 s2_0 = *(const short8*)(Wt2 + (32 + l15)*64 +  0 + quad*8);
  short8 s2_1 = *(const short8*)(Wt2 + (32 + l15)*64 + 32 + quad*8);
  short8 s3_0 = *(const short8*)(Wt2 + (48 + l15)*64 +  0 + quad*8);
  short8 s3_1 = *(const short8*)(Wt2 + (48 + l15)*64 + 32 + quad*8);
  float eb0 = bias2[l15], eb1 = bias2[16+l15], eb2 = bias2[32+l15], eb3 = bias2[48+l15];
  float e0c0=Wr2[0*64+l15], e0c1=Wr2[0*64+16+l15], e0c2=Wr2[0*64+32+l15], e0c3=Wr2[0*64+48+l15];
  float e1c0=Wr2[1*64+l15], e1c1=Wr2[1*64+16+l15], e1c2=Wr2[1*64+32+l15], e1c3=Wr2[1*64+48+l15];
  float e2c0=Wr2[2*64+l15], e2c1=Wr2[2*64+16+l15], e2c2=Wr2[2*64+32+l15], e2c3=Wr2[2*64+48+l15];

  for (int t=gw; t<ntiles; t+=nw){
    int i0 = t*16;
    for (int r=0;r<16;++r){
      int row = i0 + r;
      bool ok = row < n;
      int rr = ok ? row : n-1;
      int lb = labels[rr];
      float rx = points[rr*3+0]-centers[lb*3+0];
      float ry = points[rr*3+1]-centers[lb*3+1];
      float rz = points[rr*3+2]-centers[lb*3+2];
      float acc = bias + wr0*rx + wr1*ry + wr2*rz;
      acc += features[rr*4+0]*Wf0 + features[rr*4+1]*Wf1;
      acc += features[rr*4+2]*Wf2 + features[rr*4+3]*Wf3;
      acc = fmaxf(acc, 0.f);
      ushortT ab = f2bf(acc);
      if (ok){
        f1b[(size_t)row*64+lane] = ab;
        if (lane==0){ rel[row*3+0]=rx; rel[row*3+1]=ry; rel[row*3+2]=rz; }
      }
      lds[wslot*(16*LSTR) + r*LSTR + lane] = ab;
    }
    __builtin_amdgcn_wave_barrier();
    const ushortT* lp = lds + wslot*(16*LSTR) + l15*LSTR + quad*8;
    short8 sa0 = *(const short8*)(lp);
    short8 sa1 = *(const short8*)(lp + 32);
    __builtin_amdgcn_wave_barrier();
    v4f ec0 = {0.f,0.f,0.f,0.f}, ec1 = ec0, ec2 = ec0, ec3 = ec0;
    ec0 = __builtin_amdgcn_mfma_f32_16x16x32_bf16(sa0, s0_0, ec0, 0,0,0);
    ec1 = __builtin_amdgcn_mfma_f32_16x16x32_bf16(sa0, s1_0, ec1, 0,0,0);
    ec2 = __builtin_amdgcn_mfma_f32_16x16x32_bf16(sa0, s2_0, ec2, 0,0,0);
    ec3 = __builtin_amdgcn_mfma_f32_16x16x32_bf16(sa0, s3_0, ec3, 0,0,0);
    ec0 = __builtin_amdgcn_mfma_f32_16x16x32_bf16(sa1, s0_1, ec0, 0,0,0);
    ec1 = __builtin_amdgcn_mfma_f32_16x16x32_bf16(sa1, s1_1, ec1, 0,0,0);
    ec2 = __builtin_amdgcn_mfma_f32_16x16x32_bf16(sa1, s2_1, ec2, 0,0,0);
    ec3 = __builtin_amdgcn_mfma_f32_16x16x32_bf16(sa1, s3_1, ec3, 0,0,0);
    #pragma unroll
    for (int r=0;r<4;++r){
      int row = i0 + quad*4 + r;
      if (row < n){
        float vx=points[row*3+0], vy=points[row*3+1], vz=points[row*3+2];
        float g0 = ec0[r] + eb0 + vx*e0c0 + vy*e1c0 + vz*e2c0;
        float g1 = ec1[r] + eb1 + vx*e0c1 + vy*e1c1 + vz*e2c1;
        float g2 = ec2[r] + eb2 + vx*e0c2 + vy*e1c2 + vz*e2c2;
        float g3 = ec3[r] + eb3 + vx*e0c3 + vy*e1c3 + vz*e2c3;
        size_t base = (size_t)row*64 + l15;
        gout[base] = f2h(g0); gout[base+16] = f2h(g1); gout[base+32] = f2h(g2); gout[base+48] = f2h(g3);
      }
    }
  }
}

// ============================ MFMA GEMM with optional fused secondary GEMM ============================

template<bool RELU, int NRES, bool USEREL, bool GATHER, bool OUT16, bool F16O, int EMODE, bool ERELU>
__global__ __launch_bounds__(256) void k_gemm(
    const ushortT* __restrict__ A, const ushortT* __restrict__ Wt,
    const float* __restrict__ bias, const float* __restrict__ Wr,
    const float* __restrict__ rel, const int* __restrict__ gidx,
    const ushortT* __restrict__ r1, const ushortT* __restrict__ r2,
    ushortT* __restrict__ out16,
    const ushortT* __restrict__ Wt2, const float* __restrict__ bias2,
    const float* __restrict__ Wr2, const float* __restrict__ vec2,
    void* __restrict__ eout,
    int n, int ntiles)
{
  constexpr int LDSZ = (EMODE>0) ? 4*16*LSTR : 4;
  __shared__ ushortT lds[LDSZ];
  int tid = threadIdx.x;
  int lane = tid & 63, wslot = tid >> 6;
  int quad = lane >> 4, l15 = lane & 15;
  int gw = (blockIdx.x*256 + tid) >> 6;
  int nw = (gridDim.x*256) >> 6;

  short8 bfr0_0 = *(const short8*)(Wt + ( 0 + l15)*64 +  0 + quad*8);
  short8 bfr0_1 = *(const short8*)(Wt + ( 0 + l15)*64 + 32 + quad*8);
  short8 bfr1_0 = *(const short8*)(Wt + (16 + l15)*64 +  0 + quad*8);
  short8 bfr1_1 = *(const short8*)(Wt + (16 + l15)*64 + 32 + quad*8);
  short8 bfr2_0 = *(const short8*)(Wt + (32 + l15)*64 +  0 + quad*8);
  short8 bfr2_1 = *(const short8*)(Wt + (32 + l15)*64 + 32 + quad*8);
  short8 bfr3_0 = *(const short8*)(Wt + (48 + l15)*64 +  0 + quad*8);
  short8 bfr3_1 = *(const short8*)(Wt + (48 + l15)*64 + 32 + quad*8);
  float bs0 = bias[ 0 + l15], bs1 = bias[16 + l15];
  float bs2 = bias[32 + l15], bs3 = bias[48 + l15];
  float w0c0=0,w0c1=0,w0c2=0,w0c3=0, w1c0=0,w1c1=0,w1c2=0,w1c3=0, w2c0=0,w2c1=0,w2c2=0,w2c3=0;
  if (USEREL){
    w0c0=Wr[0*64+l15]; w0c1=Wr[0*64+16+l15]; w0c2=Wr[0*64+32+l15]; w0c3=Wr[0*64+48+l15];
    w1c0=Wr[1*64+l15]; w1c1=Wr[1*64+16+l15]; w1c2=Wr[1*64+32+l15]; w1c3=Wr[1*64+48+l15];
    w2c0=Wr[2*64+l15]; w2c1=Wr[2*64+16+l15]; w2c2=Wr[2*64+32+l15]; w2c3=Wr[2*64+48+l15];
  }

  short8 s0_0{}, s0_1{}, s1_0{}, s1_1{}, s2_0{}, s2_1{}, s3_0{}, s3_1{};
  float eb0=0, eb1=0, eb2=0, eb3=0;
  float e0c0=0,e0c1=0,e0c2=0,e0c3=0, e1c0=0,e1c1=0,e1c2=0,e1c3=0, e2c0=0,e2c1=0,e2c2=0,e2c3=0;
  float ebias_c = 0.f;
  if (EMODE == 1){
    s0_0 = *(const short8*)(Wt2 + ( 0 + l15)*64 +  0 + quad*8);
    s0_1 = *(const short8*)(Wt2 + ( 0 + l15)*64 + 32 + quad*8);
    s1_0 = *(const short8*)(Wt2 + (16 + l15)*64 +  0 + quad*8);
    s1_1 = *(const short8*)(Wt2 + (16 + l15)*64 + 32 + quad*8);
    s2_0 = *(const short8*)(Wt2 + (32 + l15)*64 +  0 + quad*8);
    s2_1 = *(const short8*)(Wt2 + (32 + l15)*64 + 32 + quad*8);
    s3_0 = *(const short8*)(Wt2 + (48 + l15)*64 +  0 + quad*8);
    s3_1 = *(const short8*)(Wt2 + (48 + l15)*64 + 32 + quad*8);
    eb0 = bias2[l15]; eb1 = bias2[16+l15]; eb2 = bias2[32+l15]; eb3 = bias2[48+l15];
    e0c0=Wr2[0*64+l15]; e0c1=Wr2[0*64+16+l15]; e0c2=Wr2[0*64+32+l15]; e0c3=Wr2[0*64+48+l15];
    e1c0=Wr2[1*64+l15]; e1c1=Wr2[1*64+16+l15]; e1c2=Wr2[1*64+32+l15]; e1c3=Wr2[1*64+48+l15];
    e2c0=Wr2[2*64+l15]; e2c1=Wr2[2*64+16+l15]; e2c2=Wr2[2*64+32+l15]; e2c3=Wr2[2*64+48+l15];
  } else if (EMODE == 2){
    s0_0 = *(const short8*)(Wt2 + l15*64 +  0 + quad*8);
    s0_1 = *(const short8*)(Wt2 + l15*64 + 32 + quad*8);
    ebias_c = (l15 < 8) ? bias2[l15] : 0.f;
  }

  for (int t=gw; t<ntiles; t+=nw){
    int i0 = t*16;
    int rowA = i0 + l15; if (rowA >= n) rowA = n-1;
    if (GATHER) rowA = gidx[rowA];
    const ushortT* ap = A + (size_t)rowA*64 + quad*8;
    short8 a0 = *(const short8*)(ap);
    short8 a1 = *(const short8*)(ap + 32);
    v4f ac0 = {0.f,0.f,0.f,0.f}, ac1 = ac0, ac2 = ac0, ac3 = ac0;
    ac0 = __builtin_amdgcn_mfma_f32_16x16x32_bf16(a0, bfr0_0, ac0, 0,0,0);
    ac1 = __builtin_amdgcn_mfma_f32_16x16x32_bf16(a0, bfr1_0, ac1, 0,0,0);
    ac2 = __builtin_amdgcn_mfma_f32_16x16x32_bf16(a0, bfr2_0, ac2, 0,0,0);
    ac3 = __builtin_amdgcn_mfma_f32_16x16x32_bf16(a0, bfr3_0, ac3, 0,0,0);
    ac0 = __builtin_amdgcn_mfma_f32_16x16x32_bf16(a1, bfr0_1, ac0, 0,0,0);
    ac1 = __builtin_amdgcn_mfma_f32_16x16x32_bf16(a1, bfr1_1, ac1, 0,0,0);
    ac2 = __builtin_amdgcn_mfma_f32_16x16x32_bf16(a1, bfr2_1, ac2, 0,0,0);
    ac3 = __builtin_amdgcn_mfma_f32_16x16x32_bf16(a1, bfr3_1, ac3, 0,0,0);

    #pragma unroll
    for (int r=0;r<4;++r){
      int row = i0 + quad*4 + r;
      bool rowok = (row < n);
      float rx=0.f, ry=0.f, rz=0.f;
      if (USEREL && rowok){ rx=rel[row*3+0]; ry=rel[row*3+1]; rz=rel[row*3+2]; }
      float v0 = ac0[r] + bs0, v1 = ac1[r] + bs1, v2 = ac2[r] + bs2, v3 = ac3[r] + bs3;
      if (USEREL){
        v0 += rx*w0c0 + ry*w1c0 + rz*w2c0;
        v1 += rx*w0c1 + ry*w1c1 + rz*w2c1;
        v2 += rx*w0c2 + ry*w1c2 + rz*w2c2;
        v3 += rx*w0c3 + ry*w1c3 + rz*w2c3;
      }
      if (RELU){ v0=fmaxf(v0,0.f); v1=fmaxf(v1,0.f); v2=fmaxf(v2,0.f); v3=fmaxf(v3,0.f); }
      size_t base = (size_t)row*64 + l15;
      if (rowok){
        if (NRES>=1){
          v0 += bf2f(r1[base]); v1 += bf2f(r1[base+16]); v2 += bf2f(r1[base+32]); v3 += bf2f(r1[base+48]);
        }
        if (NRES>=2){
          v0 += bf2f(r2[base]); v1 += bf2f(r2[base+16]); v2 += bf2f(r2[base+32]); v3 += bf2f(r2[base+48]);
        }
        if (OUT16){
          if (F16O){
            out16[base] = f2h(v0); out16[base+16] = f2h(v1); out16[base+32] = f2h(v2); out16[base+48] = f2h(v3);
          } else {
            out16[base] = f2bf(v0); out16[base+16] = f2bf(v1); out16[base+32] = f2bf(v2); out16[base+48] = f2bf(v3);
          }
        }
      }
      if (EMODE > 0){
        int lb = wslot*(16*LSTR) + (quad*4+r)*LSTR + l15;
        lds[lb]      = f2bf(v0);
        lds[lb + 16] = f2bf(v1);
        lds[lb + 32] = f2bf(v2);
        lds[lb + 48] = f2bf(v3);
      }
    }

    if (EMODE > 0){
      __builtin_amdgcn_wave_barrier();
      const ushortT* lp = lds + wslot*(16*LSTR) + l15*LSTR + quad*8;
      short8 sa0 = *(const short8*)(lp);
      short8 sa1 = *(const short8*)(lp + 32);
      __builtin_amdgcn_wave_barrier();
      if (EMODE == 1){
        v4f ec0 = {0.f,0.f,0.f,0.f}, ec1 = ec0, ec2 = ec0, ec3 = ec0;
        ec0 = __builtin_amdgcn_mfma_f32_16x16x32_bf16(sa0, s0_0, ec0, 0,0,0);
        ec1 = __builtin_amdgcn_mfma_f32_16x16x32_bf16(sa0, s1_0, ec1, 0,0,0);
        ec2 = __builtin_amdgcn_mfma_f32_16x16x32_bf16(sa0, s2_0, ec2, 0,0,0);
        ec3 = __builtin_amdgcn_mfma_f32_16x16x32_bf16(sa0, s3_0, ec3, 0,0,0);
        ec0 = __builtin_amdgcn_mfma_f32_16x16x32_bf16(sa1, s0_1, ec0, 0,0,0);
        ec1 = __builtin_amdgcn_mfma_f32_16x16x32_bf16(sa1, s1_1, ec1, 0,0,0);
        ec2 = __builtin_amdgcn_mfma_f32_16x16x32_bf16(sa1, s2_1, ec2, 0,0,0);
        ec3 = __builtin_amdgcn_mfma_f32_16x16x32_bf16(sa1, s3_1, ec3, 0,0,0);
        ushortT* eo = (ushortT*)eout;
        #pragma unroll
        for (int r=0;r<4;++r){
          int row = i0 + quad*4 + r;
          if (row < n){
            float vx=vec2[row*3+0], vy=vec2[row*3+1], vz=vec2[row*3+2];
            float g0 = ec0[r] + eb0 + vx*e0c0 + vy*e1c0 + vz*e2c0;
            float g1 = ec1[r] + eb1 + vx*e0c1 + vy*e1c1 + vz*e2c1;
            float g2 = ec2[r] + eb2 + vx*e0c2 + vy*e1c2 + vz*e2c2;
            float g3 = ec3[r] + eb3 + vx*e0c3 + vy*e1c3 + vz*e2c3;
            if (ERELU){ g0=fmaxf(g0,0.f); g1=fmaxf(g1,0.f); g2=fmaxf(g2,0.f); g3=fmaxf(g3,0.f); }
            size_t base = (size_t)row*64 + l15;
            eo[base] = f2h(g0); eo[base+16] = f2h(g1); eo[base+32] = f2h(g2); eo[base+48] = f2h(g3);
          }
        }
      } else {
        v4f ec = {0.f,0.f,0.f,0.f};
        ec = __builtin_amdgcn_mfma_f32_16x16x32_bf16(sa0, s0_0, ec, 0,0,0);
        ec = __builtin_amdgcn_mfma_f32_16x16x32_bf16(sa1, s0_1, ec, 0,0,0);
        if (l15 < 8){
          float* eo = (float*)eout;
          #pragma unroll
          for (int r=0;r<4;++r){
            int row = i0 + quad*4 + r;
            if (row < n) eo[(size_t)row*8 + l15] = ec[r] + ebias_c;
          }
        }
      }
    }
  }
}

// ============================ edge aggregation: 8 dsts/wave, 8 lanes per dst ============================
// Dedicated skinny kernel (32 VGPR, 8 waves/SIMD): all resident waves continuously issue
// gathers — fusing this into the GEMM (R13) collapsed concurrency and ran 3x slower.

__global__ __launch_bounds__(256) void k_edge_agg(const int* __restrict__ offs, const int* __restrict__ csr,
                                                  const float* __restrict__ pos, const ushortT* __restrict__ g,
                                                  const float* __restrict__ Wp, ushortT* __restrict__ agg, int n){
  int lane = threadIdx.x & 63;
  int grp = lane >> 3, d8 = lane & 7;
  int gbase = lane & 56;
  int gw = (blockIdx.x*256 + threadIdx.x) >> 6;
  int nw = (gridDim.x*256) >> 6;
  const u4v* g4 = (const u4v*)g;    // 8 u4v per 128B row
  float2 w0[4], w1[4], w2[4];
  #pragma unroll
  for (int q=0;q<4;++q){
    w0[q] = *(const float2*)(Wp + 0*64 + d8*8 + 2*q);
    w1[q] = *(const float2*)(Wp + 1*64 + 2*q + d8*8);
    w2[q] = *(const float2*)(Wp + 2*64 + d8*8 + 2*q);
  }
  const h2 NEGBIG = {(_Float16)-60000.f, (_Float16)-60000.f};
  int n8 = (n+7) >> 3;
  for (int ii=gw; ii<n8; ii+=nw){
    int i0 = ii*8;
    int ig = i0 + grp; bool ok = ig < n; if (!ok) ig = n-1;
    int b = offs[ig], e = offs[ig+1];
    int cnt = e - b, c1 = cnt - 1;
    int mx = cnt;
    mx = max(mx, __shfl_xor(mx, 8, 64));
    mx = max(mx, __shfl_xor(mx, 16, 64));
    mx = max(mx, __shfl_xor(mx, 32, 64));
    h2 m0=NEGBIG, m1=NEGBIG, m2=NEGBIG, m3=NEGBIG;
    for (int J=0; J<mx; J+=8){
      if (J < cnt){
        int sv = csr[b + min(J + d8, c1)];
        #pragma unroll
        for (int jj=0; jj<8; ++jj){
          int s = __shfl(sv, gbase + jj, 64);
          u4v u = g4[(size_t)s*8 + d8];
          m0 = pkmax(m0, u2h(u.x));
          m1 = pkmax(m1, u2h(u.y));
          m2 = pkmax(m2, u2h(u.z));
          m3 = pkmax(m3, u2h(u.w));
        }
      }
    }
    float px = pos[ig*3+0], py = pos[ig*3+1], pz = pos[ig*3+2];
    u4v outv;
    {
      float sA = w0[0].x*px + w1[0].x*py + w2[0].x*pz;
      float sB = w0[0].y*px + w1[0].y*py + w2[0].y*pz;
      outv.x = (unsigned)f2bf(fmaxf((float)m0.x - sA, 0.f)) |
               ((unsigned)f2bf(fmaxf((float)m0.y - sB, 0.f)) << 16);
    }
    {
      float sA = w0[1].x*px + w1[1].x*py + w2[1].x*pz;
      float sB = w0[1].y*px + w1[1].y*py + w2[1].y*pz;
      outv.y = (unsigned)f2bf(fmaxf((float)m1.x - sA, 0.f)) |
               ((unsigned)f2bf(fmaxf((float)m1.y - sB, 0.f)) << 16);
    }
    {
      float sA = w0[2].x*px + w1[2].x*py + w2[2].x*pz;
      float sB = w0[2].y*px + w1[2].y*py + w2[2].y*pz;
      outv.z = (unsigned)f2bf(fmaxf((float)m2.x - sA, 0.f)) |
               ((unsigned)f2bf(fmaxf((float)m2.y - sB, 0.f)) << 16);
    }
    {
      float sA = w0[3].x*px + w1[3].x*py + w2[3].x*pz;
      float sB = w0[3].y*px + w1[3].y*py + w2[3].y*pz;
      outv.w = (unsigned)f2bf(fmaxf((float)m3.x - sA, 0.f)) |
               ((unsigned)f2bf(fmaxf((float)m3.y - sB, 0.f)) << 16);
    }
    if (ok) ((u4v*)agg)[(size_t)ig*8 + d8] = outv;
  }
}

// ============================ segment sum via label CSR (f16 in, bf16 out) ============================

__global__ __launch_bounds__(256) void k_seg_gather(const int* __restrict__ offs, const int* __restrict__ csr,
                                                    const ushortT* __restrict__ h, ushortT* __restrict__ c, int m){
  int lane = threadIdx.x & 63;
  int wv = (blockIdx.x*256 + threadIdx.x) >> 6;
  if (wv >= m) return;
  int b = offs[wv], e = offs[wv+1];
  float acc = 0.f;
  for (int k=b; k<e; ++k){
    int i = csr[k];
    acc += h2f(h[(size_t)i*64+lane]);
  }
  c[(size_t)wv*64+lane] = f2bf(acc);
}

// ============================ host launcher ============================

extern "C" void kernel_launch(void* const* d_in, const int* in_sizes, int n_in,
                              void* d_out, int out_size, void* d_ws, size_t ws_size,
                              hipStream_t stream){
  const float* features = (const float*)d_in[0];
  const float* points   = (const float*)d_in[1];
  const float* centers  = (const float*)d_in[2];
  const int*   l0e      = (const int*)d_in[3];
  const int*   l1e      = (const int*)d_in[4];
  const int*   labels   = (const int*)d_in[5];
  const float* W_fe = (const float*)d_in[6];
  const float* b_fe = (const float*)d_in[7];
  const float* mWe  = (const float*)d_in[8];
  const float* mbe  = (const float*)d_in[9];
  const float* mWu  = (const float*)d_in[10];
  const float* mbu  = (const float*)d_in[11];
  const float* W_m1 = (const float*)d_in[12];
  const float* b_m1 = (const float*)d_in[13];
  const float* W_m2 = (const float*)d_in[14];
  const float* b_m2 = (const float*)d_in[15];
  const float* gWe  = (const float*)d_in[16];
  const float* gbe  = (const float*)d_in[17];
  const float* gWu  = (const float*)d_in[18];
  const float* gbu  = (const float*)d_in[19];
  const float* W_l  = (const float*)d_in[20];
  const float* b_l  = (const float*)d_in[21];
  const float* W_c  = (const float*)d_in[22];
  const float* b_c  = (const float*)d_in[23];
  float* out = (float*)d_out;

  char* w = (char*)d_ws;
  size_t off = 0;
  auto alloc = [&](size_t bytes)->void*{
    void* p = (void*)(w + off);
    off = (off + bytes + 255) & ~(size_t)255;
    return p;
  };
  float* rel  = (float*)alloc((size_t)N_PTS*3*4);
  ushortT* UF1 = (ushortT*)alloc((size_t)N_PTS*64*2);
  ushortT* UF2 = (ushortT*)alloc((size_t)N_PTS*64*2);
  ushortT* UF21= (ushortT*)alloc((size_t)N_PTS*64*2);
  ushortT* UF5 = (ushortT*)alloc((size_t)N_PTS*64*2);
  ushortT* UF6 = (ushortT*)alloc((size_t)N_PTS*64*2);
  ushortT* gbuf= (ushortT*)alloc((size_t)N_PTS*64*2);
  ushortT* abuf= (ushortT*)alloc((size_t)N_PTS*64*2);
  ushortT* cb_b= (ushortT*)alloc((size_t)M_CL*64*2);
  ushortT* UF3 = (ushortT*)alloc((size_t)M_CL*64*2);
  ushortT* UF4 = (ushortT*)alloc((size_t)M_CL*64*2);
  ushortT* cg_b= (ushortT*)alloc((size_t)M_CL*64*2);
  ushortT* cagg_b = (ushortT*)alloc((size_t)M_CL*64*2);
  ushortT* f41_b  = (ushortT*)alloc((size_t)M_CL*64*2);
  ushortT* wt  = (ushortT*)alloc((size_t)15*4096*2);
  ushortT* wtc = (ushortT*)alloc((size_t)1024*2);
  int* offs0 = (int*)alloc((size_t)(N_PTS+1)*4);
  int* csr0  = (int*)alloc((size_t)E0_N*4);
  int* offs1 = (int*)alloc((size_t)(M_CL+1)*4);
  int* csr1  = (int*)alloc((size_t)E1_N*4);
  unsigned* tmp0 = (unsigned*)alloc((size_t)NB*BCAP0*4);
  unsigned* tmp1 = (unsigned*)alloc((size_t)NB*BCAP1*4);
  int* bcur0 = (int*)alloc(NB*4);
  int* bcur1 = (int*)alloc(NB*4);
  int* bb0   = (int*)alloc(NB*4);
  int* bb1   = (int*)alloc(NB*4);
  char* zbase = (char*)alloc(0);
  int* cntL = (int*)alloc((size_t)M_CL*4);
  int* curL = (int*)alloc((size_t)M_CL*4);
  size_t zbytes = (size_t)((char*)(w+off) - zbase);
  int* offsL = (int*)alloc((size_t)(M_CL+1)*4);
  int* csrL  = (int*)alloc((size_t)N_PTS*4);
  int* partL = (int*)alloc(64*4);
  (void)ws_size; (void)in_sizes; (void)n_in; (void)out_size;

  const int NT_N = (N_PTS+15)/16;
  const int NT_M = (M_CL +15)/16;
  const int GBG_N = 1563;
  const int GBG_M = 196;
  const int GB_N  = 3125;          // 12500 waves = exactly one 8-dst unit per wave

  hipMemsetAsync(zbase, 0, zbytes, stream);

  // ---- CSR builds (256 buckets) ----
  k_binit<<<1, 256, 0, stream>>>(bcur0, bcur1);
  k_bin<RANGE0><<<256, 256, 0, stream>>>(l0e, E0_N, bcur0, tmp0);
  k_bin<RANGE1><<<196, 256, 0, stream>>>(l1e, E1_N, bcur1, tmp1);
  k_scan_bases<<<2, 64, 0, stream>>>(bcur0, bb0, offs0+N_PTS, bcur1, bb1, offs1+M_CL);
  k_csr_build<RANGE0,BCAP0><<<NB, 256, 0, stream>>>(tmp0, bcur0, bb0, N_PTS, offs0, csr0);
  k_csr_build<RANGE1,BCAP1><<<NB, 256, 0, stream>>>(tmp1, bcur1, bb1, M_CL, offs1, csr1);

  // ---- label CSR ----
  k_count_lab<<<(N_PTS+255)/256, 256, 0, stream>>>(labels, N_PTS, cntL);
  k_chunk_sum<<<7, 256, 0, stream>>>(cntL, M_CL, partL);
  k_scan_part<<<1, 64, 0, stream>>>(partL, 7, offsL, M_CL);
  k_chunk_scan<<<7, 256, 0, stream>>>(cntL, M_CL, partL, offsL);
  k_fill_lab<<<(N_PTS+255)/256, 256, 0, stream>>>(labels, N_PTS, offsL, curL, csrL);

  // ---- weight prep ----
  WSrc ws{};
  ws.p[0]=mWu+0*4096; ws.p[1]=mWu+1*4096; ws.p[2]=mWu+2*4096; ws.p[3]=mWu+3*4096;
  ws.p[4]=W_m2; ws.p[5]=gWu+0*4096; ws.p[6]=gWu+1*4096;
  ws.p[7]=mWe+0*4288+192; ws.p[8]=mWe+1*4288+192; ws.p[9]=mWe+2*4288+192; ws.p[10]=mWe+3*4288+192;
  ws.p[11]=W_m1; ws.p[12]=W_l; ws.p[13]=gWe+0*4288+192; ws.p[14]=gWe+1*4288+192;
  ws.p[15]=W_c;
  k_wprep<<<16, 256, 0, stream>>>(ws, wt, wtc);

  // ---- FUSED encoder: rel + f1 (bf16) + g0' (f16) ----
  k_f1g<<<GBG_N, 256, 0, stream>>>(features, points, centers, labels, W_fe, b_fe,
      wt+7*4096, mbe+0, mWe+0*4288, rel, UF1, gbuf, N_PTS, NT_N);

  // ---- layer0: agg -> FUSED [f2 -> UF2] + [g1' -> gbuf] ----
  k_edge_agg<<<GB_N,256,0,stream>>>(offs0, csr0, points, gbuf, mWe+0*4288, abuf, N_PTS);
  k_gemm<true,1,false,false,true,false,1,false><<<GBG_N,256,0,stream>>>(abuf, wt+0*4096, mbu+0,
      nullptr, nullptr, nullptr, UF1, nullptr, UF2,
      wt+8*4096, mbe+64, mWe+1*4288, points, gbuf, N_PTS, NT_N);
  // ---- layer1: agg -> FUSED [f2_1 -> UF21] + [h -> gbuf] ----
  k_edge_agg<<<GB_N,256,0,stream>>>(offs0, csr0, points, gbuf, mWe+1*4288, abuf, N_PTS);
  k_gemm<true,1,false,false,true,false,1,true><<<GBG_N,256,0,stream>>>(abuf, wt+1*4096, mbu+64,
      nullptr, nullptr, nullptr, UF2, nullptr, UF21,
      wt+11*4096, b_m1, W_m1+4096, rel, gbuf, N_PTS, NT_N);
  // ---- c = segsum(h); FUSED [f3 -> UF3] + [cg0' -> cg_b] ----
  k_seg_gather<<<(M_CL*64+255)/256, 256, 0, stream>>>(offsL, csrL, gbuf, cb_b, M_CL);
  k_gemm<true,0,false,false,true,false,1,false><<<GBG_M,256,0,stream>>>(cb_b, wt+4*4096, b_m2,
      nullptr, nullptr, nullptr, nullptr, nullptr, UF3,
      wt+13*4096, gbe+0, gWe+0*4288, centers, cg_b, M_CL, NT_M);
  // ---- cluster layer0: agg -> FUSED [f4 -> UF4] + [cg1' -> cg_b] ----
  k_edge_agg<<<GBG_M,256,0,stream>>>(offs1, csr1, centers, cg_b, gWe+0*4288, cagg_b, M_CL);
  k_gemm<true,1,false,false,true,false,1,false><<<GBG_M,256,0,stream>>>(cagg_b, wt+5*4096, gbu+0,
      nullptr, nullptr, nullptr, UF3, nullptr, UF4,
      wt+14*4096, gbe+64, gWe+1*4288, centers, cg_b, M_CL, NT_M);
  // ---- cluster layer1: agg -> f4_1 -> f41_b ----
  k_edge_agg<<<GBG_M,256,0,stream>>>(offs1, csr1, centers, cg_b, gWe+1*4288, cagg_b, M_CL);
  k_gemm<true,1,false,false,true,false,0,false><<<GBG_M,256,0,stream>>>(cagg_b, wt+6*4096, gbu+64,
      nullptr, nullptr, nullptr, UF4, nullptr, f41_b,
      nullptr, nullptr, nullptr, nullptr, nullptr, M_CL, NT_M);
  // ---- FUSED [f5 -> UF5] + [g2' -> gbuf] ----
  k_gemm<true,0,true,true,true,false,1,false><<<GBG_N,256,0,stream>>>(f41_b, wt+12*4096, b_l,
      W_l+4096, rel, labels, nullptr, nullptr, UF5,
      wt+9*4096, mbe+128, mWe+2*4288, points, gbuf, N_PTS, NT_N);
  // ---- layer2: agg -> FUSED [f6 = relu+f5+f2_1 -> UF6] + [g3' -> gbuf] ----
  k_edge_agg<<<GB_N,256,0,stream>>>(offs0, csr0, points, gbuf, mWe+2*4288, abuf, N_PTS);
  k_gemm<true,2,false,false,true,false,1,false><<<GBG_N,256,0,stream>>>(abuf, wt+2*4096, mbu+128,
      nullptr, nullptr, nullptr, UF5, UF21, UF6,
      wt+10*4096, mbe+192, mWe+3*4288, points, gbuf, N_PTS, NT_N);
  // ---- layer3: agg -> FUSED [final = relu+f6+f2] + [out = final@W_c + b_c] ----
  k_edge_agg<<<GB_N,256,0,stream>>>(offs0, csr0, points, gbuf, mWe+3*4288, abuf, N_PTS);
  k_gemm<true,2,false,false,false,false,2,false><<<GBG_N,256,0,stream>>>(abuf, wt+3*4096, mbu+192,
      nullptr, nullptr, nullptr, UF6, UF2, nullptr,
      wtc, b_c, nullptr, nullptr, out, N_PTS, NT_N);
}

// Round 15
// 485.490 us; speedup vs baseline: 1.5535x; 1.0822x over previous
//
#include <hip/hip_runtime.h>

#define N_PTS   100000
#define M_CL    12500
#define E0_N    1600000
#define E1_N    400000

#define NB      256
#define BIN_CAP 32
#define RANGE0  391
#define RANGE1  49           // also used for labels (ceil(12500/256))
#define BCAP0   8192
#define BCAP1   2048
#define BCAPL   1024

#define LSTR    72           // LDS row stride (shorts): 144 B, 16-B aligned

typedef unsigned short ushortT;
typedef short  short8 __attribute__((ext_vector_type(8)));
typedef float  v4f    __attribute__((ext_vector_type(4)));
typedef _Float16 h2   __attribute__((ext_vector_type(2)));
typedef unsigned u4v  __attribute__((ext_vector_type(4)));

__device__ inline ushortT f2bf(float x){
  union{float f; unsigned u;} v; v.f = x;
  unsigned r = v.u + 0x7fffu + ((v.u >> 16) & 1u);   // RNE
  return (ushortT)(r >> 16);
}
__device__ inline float bf2f(ushortT h){
  union{unsigned u; float f;} v; v.u = ((unsigned)h) << 16;
  return v.f;
}
__device__ inline ushortT f2h(float x){
  union{_Float16 h; ushortT u;} v; v.h = (_Float16)x;
  return v.u;
}
__device__ inline float h2f(ushortT u){
  union{ushortT u; _Float16 h;} v; v.u = u;
  return (float)v.h;
}
__device__ inline h2 pkmax(h2 a, h2 b){ return __builtin_elementwise_max(a, b); }
__device__ inline h2 u2h(unsigned u){ union{unsigned u; h2 h;} v{u}; return v.h; }

// ============================ weight prep + counter init (1 dispatch) ============================

struct WSrc { const float* p[16]; };

__global__ __launch_bounds__(256) void k_init_wprep(WSrc s, ushortT* __restrict__ wt, ushortT* __restrict__ wtc,
                                                    int* c0, int* c1, int* cL){
  int blk = blockIdx.x;
  if (blk == 0){
    int t = threadIdx.x;
    c0[t] = t*BCAP0; c1[t] = t*BCAP1; cL[t] = t*BCAPL;
    return;
  }
  int slot = blk - 1;
  if (slot < 15){
    const float* src = s.p[slot];
    ushortT* dst = wt + slot*4096;
    for (int e=threadIdx.x; e<4096; e+=256){
      int nn = e>>6, kk = e&63;
      dst[e] = f2bf(src[kk*64+nn]);
    }
  } else {
    const float* src = s.p[15];
    for (int e=threadIdx.x; e<1024; e+=256){
      int nn = e>>6, kk = e&63;
      wtc[e] = (nn<8) ? f2bf(src[kk*8+nn]) : (ushortT)0;
    }
  }
}

// ============================ bucketed CSR build (l0 + l1 + labels, merged) ============================
// LAB: edge e is (src=e, dst=edges[e]) — the labels list.

template<int RANGE, bool LAB>
__device__ void bin_seg(const int* __restrict__ edges, int E,
                        int* __restrict__ bcur, unsigned* __restrict__ tmp,
                        int bid, int nblk,
                        unsigned* stage, int* scnt, int* sbase){
  int tid = threadIdx.x;
  int nchunks = (E + 2047) / 2048;
  for (int c = bid; c < nchunks; c += nblk){
    int base = c*2048;
    scnt[tid] = 0;
    __syncthreads();
    #pragma unroll
    for (int r=0;r<8;++r){
      int e = base + r*256 + tid;
      if (e < E){
        int s, d;
        if (LAB){ s = e; d = edges[e]; }
        else    { s = edges[2*e]; d = edges[2*e+1]; }
        int bk = d / RANGE;
        unsigned packed = ((unsigned)s << 11) | (unsigned)(d - bk*RANGE);
        int pos = atomicAdd(&scnt[bk], 1);
        if (pos < BIN_CAP) stage[bk*BIN_CAP+pos] = packed;
        else tmp[atomicAdd(&bcur[bk],1)] = packed;
      }
    }
    __syncthreads();
    {
      int nfl = scnt[tid]; if (nfl > BIN_CAP) nfl = BIN_CAP;
      sbase[tid] = atomicAdd(&bcur[tid], nfl);
    }
    __syncthreads();
    int wv = tid >> 6, ln = tid & 63;
    for (int bb=0; bb<32; ++bb){
      int bk = wv*64 + bb*2 + (ln>>5);
      int ent = ln & 31;
      int nf = scnt[bk]; if (nf > BIN_CAP) nf = BIN_CAP;
      if (ent < nf) tmp[sbase[bk]+ent] = stage[bk*BIN_CAP+ent];
    }
    __syncthreads();
  }
}

__global__ __launch_bounds__(256) void k_bin_all(const int* __restrict__ l0e, const int* __restrict__ l1e,
                                                 const int* __restrict__ labels,
                                                 int* bc0, int* bc1, int* bcL,
                                                 unsigned* t0, unsigned* t1, unsigned* tL){
  __shared__ unsigned stage[NB*BIN_CAP];
  __shared__ int scnt[NB];
  __shared__ int sbase[NB];
  int b = blockIdx.x;
  if (b < 256)      bin_seg<RANGE0,false>(l0e, E0_N, bc0, t0, b, 256, stage, scnt, sbase);
  else if (b < 452) bin_seg<RANGE1,false>(l1e, E1_N, bc1, t1, b-256, 196, stage, scnt, sbase);
  else              bin_seg<RANGE1,true >(labels, N_PTS, bcL, tL, b-452, 49, stage, scnt, sbase);
}

// exclusive scan of 256 bucket counts; blocks: 0->l0, 1->l1, 2->labels
__global__ void k_scan_all(const int* c0, int* bb0, int* e0,
                           const int* c1, int* bb1, int* e1,
                           const int* cL, int* bbL, int* eL){
  const int* cur; int* bb; int* offe; int BC;
  if (blockIdx.x == 0){ cur=c0; bb=bb0; offe=e0; BC=BCAP0; }
  else if (blockIdx.x == 1){ cur=c1; bb=bb1; offe=e1; BC=BCAP1; }
  else { cur=cL; bb=bbL; offe=eL; BC=BCAPL; }
  int lane = threadIdx.x & 63;
  int base = lane*4;
  int v0 = cur[base+0] - (base+0)*BC;
  int v1 = cur[base+1] - (base+1)*BC;
  int v2 = cur[base+2] - (base+2)*BC;
  int v3 = cur[base+3] - (base+3)*BC;
  int psum = v0+v1+v2+v3, sc = psum;
  #pragma unroll
  for (int st=1; st<64; st<<=1){
    int x = __shfl_up(sc, st, 64);
    if (lane >= st) sc += x;
  }
  int ex = sc - psum;
  bb[base+0] = ex;
  bb[base+1] = ex + v0;
  bb[base+2] = ex + v0 + v1;
  bb[base+3] = ex + v0 + v1 + v2;
  if (lane == 63) *offe = sc;
}

template<int RANGE, int BCAP, int K>
__device__ void csr_build_seg(const unsigned* __restrict__ tmp, const int* __restrict__ bcur,
                              const int* __restrict__ bb, int n,
                              int* __restrict__ offs, int* __restrict__ csr,
                              int b, int* hist, int* part){
  int tid = threadIdx.x;
  int dlo = b*RANGE;
  int range = n - dlo; if (range > RANGE) range = RANGE; if (range < 0) range = 0;
  int cnt = bcur[b] - b*BCAP;
  for (int t=tid; t<RANGE; t+=256) hist[t] = 0;
  __syncthreads();
  const unsigned* sl = tmp + (size_t)b*BCAP;
  for (int j=tid; j<cnt; j+=256) atomicAdd(&hist[sl[j] & 2047u], 1);
  __syncthreads();
  int s = 0; int loc[K];
  #pragma unroll
  for (int kk=0; kk<K; ++kk){
    int idx = tid*K + kk;
    int v = (idx < RANGE) ? hist[idx] : 0;
    loc[kk] = s; s += v;
  }
  part[tid] = s; __syncthreads();
  int own = s;
  for (int st=1; st<256; st<<=1){
    int x = (tid >= st) ? part[tid-st] : 0;
    __syncthreads();
    part[tid] += x;
    __syncthreads();
  }
  int ebase = part[tid] - own;
  int gb = bb[b];
  __syncthreads();
  #pragma unroll
  for (int kk=0; kk<K; ++kk){
    int idx = tid*K + kk;
    if (idx < RANGE){
      int ex = ebase + loc[kk];
      if (idx < range) offs[dlo+idx] = gb + ex;
      hist[idx] = ex;
    }
  }
  __syncthreads();
  for (int j=tid; j<cnt; j+=256){
    unsigned p = sl[j];
    int pos = atomicAdd(&hist[p & 2047u], 1);
    csr[gb + pos] = (int)(p >> 11);
  }
}

__global__ __launch_bounds__(256) void k_build_all(
    const unsigned* t0, const int* bc0, const int* bb0, int* offs0, int* csr0,
    const unsigned* t1, const int* bc1, const int* bb1, int* offs1, int* csr1,
    const unsigned* tL, const int* bcL, const int* bbL, int* offsL, int* csrL){
  __shared__ int hist[RANGE0];
  __shared__ int part[256];
  int b = blockIdx.x;
  if (b < 256)      csr_build_seg<RANGE0,BCAP0,2>(t0, bc0, bb0, N_PTS, offs0, csr0, b, hist, part);
  else if (b < 512) csr_build_seg<RANGE1,BCAP1,1>(t1, bc1, bb1, M_CL, offs1, csr1, b-256, hist, part);
  else              csr_build_seg<RANGE1,BCAPL,1>(tL, bcL, bbL, M_CL, offsL, csrL, b-512, hist, part);
}

// ============================ fused encoder: rel + f1(bf16) + g0'(f16 via MFMA) ============================

__global__ __launch_bounds__(256) void k_f1g(const float* __restrict__ features, const float* __restrict__ points,
                                             const float* __restrict__ centers, const int* __restrict__ labels,
                                             const float* __restrict__ W, const float* __restrict__ b,
                                             const ushortT* __restrict__ Wt2, const float* __restrict__ bias2,
                                             const float* __restrict__ Wr2,
                                             float* __restrict__ rel, ushortT* __restrict__ f1b,
                                             ushortT* __restrict__ gout, int n, int ntiles){
  __shared__ ushortT lds[4*16*LSTR];
  int tid = threadIdx.x;
  int lane = tid & 63, wslot = tid >> 6;
  int quad = lane >> 4, l15 = lane & 15;
  int gw = (blockIdx.x*256 + tid) >> 6;
  int nw = (gridDim.x*256) >> 6;
  float Wf0=W[0*64+lane], Wf1=W[1*64+lane], Wf2=W[2*64+lane], Wf3=W[3*64+lane];
  float wr0=W[4*64+lane], wr1=W[5*64+lane], wr2=W[6*64+lane];
  float bias=b[lane];
  short8 s0_0 = *(const short8*)(Wt2 + ( 0 + l15)*64 +  0 + quad*8);
  short8 s0_1 = *(const short8*)(Wt2 + ( 0 + l15)*64 + 32 + quad*8);
  short8 s1_0 = *(const short8*)(Wt2 + (16 + l15)*64 +  0 + quad*8);
  short8 s1_1 = *(const short8*)(Wt2 + (16 + l15)*64 + 32 + quad*8);
  short8 s2_0 = *(const short8*)(Wt2 + (32 + l15)*64 +  0 + quad*8);
  short8 s2_1 = *(const short8*)(Wt2 + (32 + l15)*64 + 32 + quad*8);
  short8 s3_0 = *(const short8*)(Wt2 + (48 + l15)*64 +  0 + quad*8);
  short8 s3_1 = *(const short8*)(Wt2 + (48 + l15)*64 + 32 + quad*8);
  float eb0 = bias2[l15], eb1 = bias2[16+l15], eb2 = bias2[32+l15], eb3 = bias2[48+l15];
  float e0c0=Wr2[0*64+l15], e0c1=Wr2[0*64+16+l15], e0c2=Wr2[0*64+32+l15], e0c3=Wr2[0*64+48+l15];
  float e1c0=Wr2[1*64+l15], e1c1=Wr2[1*64+16+l15], e1c2=Wr2[1*64+32+l15], e1c3=Wr2[1*64+48+l15];
  float e2c0=Wr2[2*64+l15], e2c1=Wr2[2*64+16+l15], e2c2=Wr2[2*64+32+l15], e2c3=Wr2[2*64+48+l15];

  for (int t=gw; t<ntiles; t+=nw){
    int i0 = t*16;
    for (int r=0;r<16;++r){
      int row = i0 + r;
      bool ok = row < n;
      int rr = ok ? row : n-1;
      int lb = labels[rr];
      float rx = points[rr*3+0]-centers[lb*3+0];
      float ry = points[rr*3+1]-centers[lb*3+1];
      float rz = points[rr*3+2]-centers[lb*3+2];
      float acc = bias + wr0*rx + wr1*ry + wr2*rz;
      acc += features[rr*4+0]*Wf0 + features[rr*4+1]*Wf1;
      acc += features[rr*4+2]*Wf2 + features[rr*4+3]*Wf3;
      acc = fmaxf(acc, 0.f);
      ushortT ab = f2bf(acc);
      if (ok){
        f1b[(size_t)row*64+lane] = ab;
        if (lane==0){ rel[row*3+0]=rx; rel[row*3+1]=ry; rel[row*3+2]=rz; }
      }
      lds[wslot*(16*LSTR) + r*LSTR + lane] = ab;
    }
    __builtin_amdgcn_wave_barrier();
    const ushortT* lp = lds + wslot*(16*LSTR) + l15*LSTR + quad*8;
    short8 sa0 = *(const short8*)(lp);
    short8 sa1 = *(const short8*)(lp + 32);
    __builtin_amdgcn_wave_barrier();
    v4f ec0 = {0.f,0.f,0.f,0.f}, ec1 = ec0, ec2 = ec0, ec3 = ec0;
    ec0 = __builtin_amdgcn_mfma_f32_16x16x32_bf16(sa0, s0_0, ec0, 0,0,0);
    ec1 = __builtin_amdgcn_mfma_f32_16x16x32_bf16(sa0, s1_0, ec1, 0,0,0);
    ec2 = __builtin_amdgcn_mfma_f32_16x16x32_bf16(sa0, s2_0, ec2, 0,0,0);
    ec3 = __builtin_amdgcn_mfma_f32_16x16x32_bf16(sa0, s3_0, ec3, 0,0,0);
    ec0 = __builtin_amdgcn_mfma_f32_16x16x32_bf16(sa1, s0_1, ec0, 0,0,0);
    ec1 = __builtin_amdgcn_mfma_f32_16x16x32_bf16(sa1, s1_1, ec1, 0,0,0);
    ec2 = __builtin_amdgcn_mfma_f32_16x16x32_bf16(sa1, s2_1, ec2, 0,0,0);
    ec3 = __builtin_amdgcn_mfma_f32_16x16x32_bf16(sa1, s3_1, ec3, 0,0,0);
    #pragma unroll
    for (int r=0;r<4;++r){
      int row = i0 + quad*4 + r;
      if (row < n){
        float vx=points[row*3+0], vy=points[row*3+1], vz=points[row*3+2];
        float g0 = ec0[r] + eb0 + vx*e0c0 + vy*e1c0 + vz*e2c0;
        float g1 = ec1[r] + eb1 + vx*e0c1 + vy*e1c1 + vz*e2c1;
        float g2 = ec2[r] + eb2 + vx*e0c2 + vy*e1c2 + vz*e2c2;
        float g3 = ec3[r] + eb3 + vx*e0c3 + vy*e1c3 + vz*e2c3;
        size_t base = (size_t)row*64 + l15;
        gout[base] = f2h(g0); gout[base+16] = f2h(g1); gout[base+32] = f2h(g2); gout[base+48] = f2h(g3);
      }
    }
  }
}

// ============================ MFMA GEMM with optional fused secondary GEMM ============================

template<bool RELU, int NRES, bool USEREL, bool GATHER, bool OUT16, bool F16O, int EMODE, bool ERELU>
__global__ __launch_bounds__(256) void k_gemm(
    const ushortT* __restrict__ A, const ushortT* __restrict__ Wt,
    const float* __restrict__ bias, const float* __restrict__ Wr,
    const float* __restrict__ rel, const int* __restrict__ gidx,
    const ushortT* __restrict__ r1, const ushortT* __restrict__ r2,
    ushortT* __restrict__ out16,
    const ushortT* __restrict__ Wt2, const float* __restrict__ bias2,
    const float* __restrict__ Wr2, const float* __restrict__ vec2,
    void* __restrict__ eout,
    int n, int ntiles)
{
  constexpr int LDSZ = (EMODE>0) ? 4*16*LSTR : 4;
  __shared__ ushortT lds[LDSZ];
  int tid = threadIdx.x;
  int lane = tid & 63, wslot = tid >> 6;
  int quad = lane >> 4, l15 = lane & 15;
  int gw = (blockIdx.x*256 + tid) >> 6;
  int nw = (gridDim.x*256) >> 6;

  short8 bfr0_0 = *(const short8*)(Wt + ( 0 + l15)*64 +  0 + quad*8);
  short8 bfr0_1 = *(const short8*)(Wt + ( 0 + l15)*64 + 32 + quad*8);
  short8 bfr1_0 = *(const short8*)(Wt + (16 + l15)*64 +  0 + quad*8);
  short8 bfr1_1 = *(const short8*)(Wt + (16 + l15)*64 + 32 + quad*8);
  short8 bfr2_0 = *(const short8*)(Wt + (32 + l15)*64 +  0 + quad*8);
  short8 bfr2_1 = *(const short8*)(Wt + (32 + l15)*64 + 32 + quad*8);
  short8 bfr3_0 = *(const short8*)(Wt + (48 + l15)*64 +  0 + quad*8);
  short8 bfr3_1 = *(const short8*)(Wt + (48 + l15)*64 + 32 + quad*8);
  float bs0 = bias[ 0 + l15], bs1 = bias[16 + l15];
  float bs2 = bias[32 + l15], bs3 = bias[48 + l15];
  float w0c0=0,w0c1=0,w0c2=0,w0c3=0, w1c0=0,w1c1=0,w1c2=0,w1c3=0, w2c0=0,w2c1=0,w2c2=0,w2c3=0;
  if (USEREL){
    w0c0=Wr[0*64+l15]; w0c1=Wr[0*64+16+l15]; w0c2=Wr[0*64+32+l15]; w0c3=Wr[0*64+48+l15];
    w1c0=Wr[1*64+l15]; w1c1=Wr[1*64+16+l15]; w1c2=Wr[1*64+32+l15]; w1c3=Wr[1*64+48+l15];
    w2c0=Wr[2*64+l15]; w2c1=Wr[2*64+16+l15]; w2c2=Wr[2*64+32+l15]; w2c3=Wr[2*64+48+l15];
  }

  short8 s0_0{}, s0_1{}, s1_0{}, s1_1{}, s2_0{}, s2_1{}, s3_0{}, s3_1{};
  float eb0=0, eb1=0, eb2=0, eb3=0;
  float e0c0=0,e0c1=0,e0c2=0,e0c3=0, e1c0=0,e1c1=0,e1c2=0,e1c3=0, e2c0=0,e2c1=0,e2c2=0,e2c3=0;
  float ebias_c = 0.f;
  if (EMODE == 1){
    s0_0 = *(const short8*)(Wt2 + ( 0 + l15)*64 +  0 + quad*8);
    s0_1 = *(const short8*)(Wt2 + ( 0 + l15)*64 + 32 + quad*8);
    s1_0 = *(const short8*)(Wt2 + (16 + l15)*64 +  0 + quad*8);
    s1_1 = *(const short8*)(Wt2 + (16 + l15)*64 + 32 + quad*8);
    s2_0 = *(const short8*)(Wt2 + (32 + l15)*64 +  0 + quad*8);
    s2_1 = *(const short8*)(Wt2 + (32 + l15)*64 + 32 + quad*8);
    s3_0 = *(const short8*)(Wt2 + (48 + l15)*64 +  0 + quad*8);
    s3_1 = *(const short8*)(Wt2 + (48 + l15)*64 + 32 + quad*8);
    eb0 = bias2[l15]; eb1 = bias2[16+l15]; eb2 = bias2[32+l15]; eb3 = bias2[48+l15];
    e0c0=Wr2[0*64+l15]; e0c1=Wr2[0*64+16+l15]; e0c2=Wr2[0*64+32+l15]; e0c3=Wr2[0*64+48+l15];
    e1c0=Wr2[1*64+l15]; e1c1=Wr2[1*64+16+l15]; e1c2=Wr2[1*64+32+l15]; e1c3=Wr2[1*64+48+l15];
    e2c0=Wr2[2*64+l15]; e2c1=Wr2[2*64+16+l15]; e2c2=Wr2[2*64+32+l15]; e2c3=Wr2[2*64+48+l15];
  } else if (EMODE == 2){
    s0_0 = *(const short8*)(Wt2 + l15*64 +  0 + quad*8);
    s0_1 = *(const short8*)(Wt2 + l15*64 + 32 + quad*8);
    ebias_c = (l15 < 8) ? bias2[l15] : 0.f;
  }

  for (int t=gw; t<ntiles; t+=nw){
    int i0 = t*16;
    int rowA = i0 + l15; if (rowA >= n) rowA = n-1;
    if (GATHER) rowA = gidx[rowA];
    const ushortT* ap = A + (size_t)rowA*64 + quad*8;
    short8 a0 = *(const short8*)(ap);
    short8 a1 = *(const short8*)(ap + 32);
    v4f ac0 = {0.f,0.f,0.f,0.f}, ac1 = ac0, ac2 = ac0, ac3 = ac0;
    ac0 = __builtin_amdgcn_mfma_f32_16x16x32_bf16(a0, bfr0_0, ac0, 0,0,0);
    ac1 = __builtin_amdgcn_mfma_f32_16x16x32_bf16(a0, bfr1_0, ac1, 0,0,0);
    ac2 = __builtin_amdgcn_mfma_f32_16x16x32_bf16(a0, bfr2_0, ac2, 0,0,0);
    ac3 = __builtin_amdgcn_mfma_f32_16x16x32_bf16(a0, bfr3_0, ac3, 0,0,0);
    ac0 = __builtin_amdgcn_mfma_f32_16x16x32_bf16(a1, bfr0_1, ac0, 0,0,0);
    ac1 = __builtin_amdgcn_mfma_f32_16x16x32_bf16(a1, bfr1_1, ac1, 0,0,0);
    ac2 = __builtin_amdgcn_mfma_f32_16x16x32_bf16(a1, bfr2_1, ac2, 0,0,0);
    ac3 = __builtin_amdgcn_mfma_f32_16x16x32_bf16(a1, bfr3_1, ac3, 0,0,0);

    #pragma unroll
    for (int r=0;r<4;++r){
      int row = i0 + quad*4 + r;
      bool rowok = (row < n);
      float rx=0.f, ry=0.f, rz=0.f;
      if (USEREL && rowok){ rx=rel[row*3+0]; ry=rel[row*3+1]; rz=rel[row*3+2]; }
      float v0 = ac0[r] + bs0, v1 = ac1[r] + bs1, v2 = ac2[r] + bs2, v3 = ac3[r] + bs3;
      if (USEREL){
        v0 += rx*w0c0 + ry*w1c0 + rz*w2c0;
        v1 += rx*w0c1 + ry*w1c1 + rz*w2c1;
        v2 += rx*w0c2 + ry*w1c2 + rz*w2c2;
        v3 += rx*w0c3 + ry*w1c3 + rz*w2c3;
      }
      if (RELU){ v0=fmaxf(v0,0.f); v1=fmaxf(v1,0.f); v2=fmaxf(v2,0.f); v3=fmaxf(v3,0.f); }
      size_t base = (size_t)row*64 + l15;
      if (rowok){
        if (NRES>=1){
          v0 += bf2f(r1[base]); v1 += bf2f(r1[base+16]); v2 += bf2f(r1[base+32]); v3 += bf2f(r1[base+48]);
        }
        if (NRES>=2){
          v0 += bf2f(r2[base]); v1 += bf2f(r2[base+16]); v2 += bf2f(r2[base+32]); v3 += bf2f(r2[base+48]);
        }
        if (OUT16){
          if (F16O){
            out16[base] = f2h(v0); out16[base+16] = f2h(v1); out16[base+32] = f2h(v2); out16[base+48] = f2h(v3);
          } else {
            out16[base] = f2bf(v0); out16[base+16] = f2bf(v1); out16[base+32] = f2bf(v2); out16[base+48] = f2bf(v3);
          }
        }
      }
      if (EMODE > 0){
        int lb = wslot*(16*LSTR) + (quad*4+r)*LSTR + l15;
        lds[lb]      = f2bf(v0);
        lds[lb + 16] = f2bf(v1);
        lds[lb + 32] = f2bf(v2);
        lds[lb + 48] = f2bf(v3);
      }
    }

    if (EMODE > 0){
      __builtin_amdgcn_wave_barrier();
      const ushortT* lp = lds + wslot*(16*LSTR) + l15*LSTR + quad*8;
      short8 sa0 = *(const short8*)(lp);
      short8 sa1 = *(const short8*)(lp + 32);
      __builtin_amdgcn_wave_barrier();
      if (EMODE == 1){
        v4f ec0 = {0.f,0.f,0.f,0.f}, ec1 = ec0, ec2 = ec0, ec3 = ec0;
        ec0 = __builtin_amdgcn_mfma_f32_16x16x32_bf16(sa0, s0_0, ec0, 0,0,0);
        ec1 = __builtin_amdgcn_mfma_f32_16x16x32_bf16(sa0, s1_0, ec1, 0,0,0);
        ec2 = __builtin_amdgcn_mfma_f32_16x16x32_bf16(sa0, s2_0, ec2, 0,0,0);
        ec3 = __builtin_amdgcn_mfma_f32_16x16x32_bf16(sa0, s3_0, ec3, 0,0,0);
        ec0 = __builtin_amdgcn_mfma_f32_16x16x32_bf16(sa1, s0_1, ec0, 0,0,0);
        ec1 = __builtin_amdgcn_mfma_f32_16x16x32_bf16(sa1, s1_1, ec1, 0,0,0);
        ec2 = __builtin_amdgcn_mfma_f32_16x16x32_bf16(sa1, s2_1, ec2, 0,0,0);
        ec3 = __builtin_amdgcn_mfma_f32_16x16x32_bf16(sa1, s3_1, ec3, 0,0,0);
        ushortT* eo = (ushortT*)eout;
        #pragma unroll
        for (int r=0;r<4;++r){
          int row = i0 + quad*4 + r;
          if (row < n){
            float vx=vec2[row*3+0], vy=vec2[row*3+1], vz=vec2[row*3+2];
            float g0 = ec0[r] + eb0 + vx*e0c0 + vy*e1c0 + vz*e2c0;
            float g1 = ec1[r] + eb1 + vx*e0c1 + vy*e1c1 + vz*e2c1;
            float g2 = ec2[r] + eb2 + vx*e0c2 + vy*e1c2 + vz*e2c2;
            float g3 = ec3[r] + eb3 + vx*e0c3 + vy*e1c3 + vz*e2c3;
            if (ERELU){ g0=fmaxf(g0,0.f); g1=fmaxf(g1,0.f); g2=fmaxf(g2,0.f); g3=fmaxf(g3,0.f); }
            size_t base = (size_t)row*64 + l15;
            eo[base] = f2h(g0); eo[base+16] = f2h(g1); eo[base+32] = f2h(g2); eo[base+48] = f2h(g3);
          }
        }
      } else {
        v4f ec = {0.f,0.f,0.f,0.f};
        ec = __builtin_amdgcn_mfma_f32_16x16x32_bf16(sa0, s0_0, ec, 0,0,0);
        ec = __builtin_amdgcn_mfma_f32_16x16x32_bf16(sa1, s0_1, ec, 0,0,0);
        if (l15 < 8){
          float* eo = (float*)eout;
          #pragma unroll
          for (int r=0;r<4;++r){
            int row = i0 + quad*4 + r;
            if (row < n) eo[(size_t)row*8 + l15] = ec[r] + ebias_c;
          }
        }
      }
    }
  }
}

// ============================ edge aggregation: 8 dsts/wave, 8 lanes per dst ============================
// Dedicated skinny kernel (32 VGPR, max occupancy): all resident waves continuously issue
// gathers — fusing this into the GEMM (R13) collapsed concurrency and ran 3x slower.

__global__ __launch_bounds__(256) void k_edge_agg(const int* __restrict__ offs, const int* __restrict__ csr,
                                                  const float* __restrict__ pos, const ushortT* __restrict__ g,
                                                  const float* __restrict__ Wp, ushortT* __restrict__ agg, int n){
  int lane = threadIdx.x & 63;
  int grp = lane >> 3, d8 = lane & 7;
  int gbase = lane & 56;
  int gw = (blockIdx.x*256 + threadIdx.x) >> 6;
  int nw = (gridDim.x*256) >> 6;
  const u4v* g4 = (const u4v*)g;
  float2 w0[4], w1[4], w2[4];
  #pragma unroll
  for (int q=0;q<4;++q){
    w0[q] = *(const float2*)(Wp + 0*64 + d8*8 + 2*q);
    w1[q] = *(const float2*)(Wp + 1*64 + d8*8 + 2*q);
    w2[q] = *(const float2*)(Wp + 2*64 + d8*8 + 2*q);
  }
  const h2 NEGBIG = {(_Float16)-60000.f, (_Float16)-60000.f};
  int n8 = (n+7) >> 3;
  for (int ii=gw; ii<n8; ii+=nw){
    int i0 = ii*8;
    int ig = i0 + grp; bool ok = ig < n; if (!ok) ig = n-1;
    int b = offs[ig], e = offs[ig+1];
    int cnt = e - b, c1 = cnt - 1;
    int mx = cnt;
    mx = max(mx, __shfl_xor(mx, 8, 64));
    mx = max(mx, __shfl_xor(mx, 16, 64));
    mx = max(mx, __shfl_xor(mx, 32, 64));
    h2 m0=NEGBIG, m1=NEGBIG, m2=NEGBIG, m3=NEGBIG;
    for (int J=0; J<mx; J+=8){
      if (J < cnt){
        int sv = csr[b + min(J + d8, c1)];
        #pragma unroll
        for (int jj=0; jj<8; ++jj){
          int s = __shfl(sv, gbase + jj, 64);
          u4v u = g4[(size_t)s*8 + d8];
          m0 = pkmax(m0, u2h(u.x));
          m1 = pkmax(m1, u2h(u.y));
          m2 = pkmax(m2, u2h(u.z));
          m3 = pkmax(m3, u2h(u.w));
        }
      }
    }
    float px = pos[ig*3+0], py = pos[ig*3+1], pz = pos[ig*3+2];
    u4v outv;
    {
      float sA = w0[0].x*px + w1[0].x*py + w2[0].x*pz;
      float sB = w0[0].y*px + w1[0].y*py + w2[0].y*pz;
      outv.x = (unsigned)f2bf(fmaxf((float)m0.x - sA, 0.f)) |
               ((unsigned)f2bf(fmaxf((float)m0.y - sB, 0.f)) << 16);
    }
    {
      float sA = w0[1].x*px + w1[1].x*py + w2[1].x*pz;
      float sB = w0[1].y*px + w1[1].y*py + w2[1].y*pz;
      outv.y = (unsigned)f2bf(fmaxf((float)m1.x - sA, 0.f)) |
               ((unsigned)f2bf(fmaxf((float)m1.y - sB, 0.f)) << 16);
    }
    {
      float sA = w0[2].x*px + w1[2].x*py + w2[2].x*pz;
      float sB = w0[2].y*px + w1[2].y*py + w2[2].y*pz;
      outv.z = (unsigned)f2bf(fmaxf((float)m2.x - sA, 0.f)) |
               ((unsigned)f2bf(fmaxf((float)m2.y - sB, 0.f)) << 16);
    }
    {
      float sA = w0[3].x*px + w1[3].x*py + w2[3].x*pz;
      float sB = w0[3].y*px + w1[3].y*py + w2[3].y*pz;
      outv.w = (unsigned)f2bf(fmaxf((float)m3.x - sA, 0.f)) |
               ((unsigned)f2bf(fmaxf((float)m3.y - sB, 0.f)) << 16);
    }
    if (ok) ((u4v*)agg)[(size_t)ig*8 + d8] = outv;
  }
}

// ============================ segment sum via label CSR (f16 in, bf16 out) ============================

__global__ __launch_bounds__(256) void k_seg_gather(const int* __restrict__ offs, const int* __restrict__ csr,
                                                    const ushortT* __restrict__ h, ushortT* __restrict__ c, int m){
  int lane = threadIdx.x & 63;
  int wv = (blockIdx.x*256 + threadIdx.x) >> 6;
  if (wv >= m) return;
  int b = offs[wv], e = offs[wv+1];
  float acc = 0.f;
  for (int k=b; k<e; ++k){
    int i = csr[k];
    acc += h2f(h[(size_t)i*64+lane]);
  }
  c[(size_t)wv*64+lane] = f2bf(acc);
}

// ============================ host launcher ============================

extern "C" void kernel_launch(void* const* d_in, const int* in_sizes, int n_in,
                              void* d_out, int out_size, void* d_ws, size_t ws_size,
                              hipStream_t stream){
  const float* features = (const float*)d_in[0];
  const float* points   = (const float*)d_in[1];
  const float* centers  = (const float*)d_in[2];
  const int*   l0e      = (const int*)d_in[3];
  const int*   l1e      = (const int*)d_in[4];
  const int*   labels   = (const int*)d_in[5];
  const float* W_fe = (const float*)d_in[6];
  const float* b_fe = (const float*)d_in[7];
  const float* mWe  = (const float*)d_in[8];
  const float* mbe  = (const float*)d_in[9];
  const float* mWu  = (const float*)d_in[10];
  const float* mbu  = (const float*)d_in[11];
  const float* W_m1 = (const float*)d_in[12];
  const float* b_m1 = (const float*)d_in[13];
  const float* W_m2 = (const float*)d_in[14];
  const float* b_m2 = (const float*)d_in[15];
  const float* gWe  = (const float*)d_in[16];
  const float* gbe  = (const float*)d_in[17];
  const float* gWu  = (const float*)d_in[18];
  const float* gbu  = (const float*)d_in[19];
  const float* W_l  = (const float*)d_in[20];
  const float* b_l  = (const float*)d_in[21];
  const float* W_c  = (const float*)d_in[22];
  const float* b_c  = (const float*)d_in[23];
  float* out = (float*)d_out;

  char* w = (char*)d_ws;
  size_t off = 0;
  auto alloc = [&](size_t bytes)->void*{
    void* p = (void*)(w + off);
    off = (off + bytes + 255) & ~(size_t)255;
    return p;
  };
  float* rel  = (float*)alloc((size_t)N_PTS*3*4);
  ushortT* UF1 = (ushortT*)alloc((size_t)N_PTS*64*2);
  ushortT* UF2 = (ushortT*)alloc((size_t)N_PTS*64*2);
  ushortT* UF21= (ushortT*)alloc((size_t)N_PTS*64*2);
  ushortT* UF5 = (ushortT*)alloc((size_t)N_PTS*64*2);
  ushortT* UF6 = (ushortT*)alloc((size_t)N_PTS*64*2);
  ushortT* gbuf= (ushortT*)alloc((size_t)N_PTS*64*2);
  ushortT* abuf= (ushortT*)alloc((size_t)N_PTS*64*2);
  ushortT* cb_b= (ushortT*)alloc((size_t)M_CL*64*2);
  ushortT* UF3 = (ushortT*)alloc((size_t)M_CL*64*2);
  ushortT* UF4 = (ushortT*)alloc((size_t)M_CL*64*2);
  ushortT* cg_b= (ushortT*)alloc((size_t)M_CL*64*2);
  ushortT* cagg_b = (ushortT*)alloc((size_t)M_CL*64*2);
  ushortT* f41_b  = (ushortT*)alloc((size_t)M_CL*64*2);
  ushortT* wt  = (ushortT*)alloc((size_t)15*4096*2);
  ushortT* wtc = (ushortT*)alloc((size_t)1024*2);
  int* offs0 = (int*)alloc((size_t)(N_PTS+1)*4);
  int* csr0  = (int*)alloc((size_t)E0_N*4);
  int* offs1 = (int*)alloc((size_t)(M_CL+1)*4);
  int* csr1  = (int*)alloc((size_t)E1_N*4);
  int* offsL = (int*)alloc((size_t)(M_CL+1)*4);
  int* csrL  = (int*)alloc((size_t)N_PTS*4);
  unsigned* tmp0 = (unsigned*)alloc((size_t)NB*BCAP0*4);
  unsigned* tmp1 = (unsigned*)alloc((size_t)NB*BCAP1*4);
  unsigned* tmpL = (unsigned*)alloc((size_t)NB*BCAPL*4);
  int* bcur0 = (int*)alloc(NB*4);
  int* bcur1 = (int*)alloc(NB*4);
  int* bcurL = (int*)alloc(NB*4);
  int* bb0   = (int*)alloc(NB*4);
  int* bb1   = (int*)alloc(NB*4);
  int* bbL   = (int*)alloc(NB*4);
  (void)ws_size; (void)in_sizes; (void)n_in; (void)out_size;

  const int NT_N = (N_PTS+15)/16;
  const int NT_M = (M_CL +15)/16;
  const int GBG_N = 1563;
  const int GBG_M = 196;
  const int GB_N  = 3125;

  // ---- setup: weights + counters (1), bin all three lists (1), scan (1), build (1) ----
  WSrc ws{};
  ws.p[0]=mWu+0*4096; ws.p[1]=mWu+1*4096; ws.p[2]=mWu+2*4096; ws.p[3]=mWu+3*4096;
  ws.p[4]=W_m2; ws.p[5]=gWu+0*4096; ws.p[6]=gWu+1*4096;
  ws.p[7]=mWe+0*4288+192; ws.p[8]=mWe+1*4288+192; ws.p[9]=mWe+2*4288+192; ws.p[10]=mWe+3*4288+192;
  ws.p[11]=W_m1; ws.p[12]=W_l; ws.p[13]=gWe+0*4288+192; ws.p[14]=gWe+1*4288+192;
  ws.p[15]=W_c;
  k_init_wprep<<<17, 256, 0, stream>>>(ws, wt, wtc, bcur0, bcur1, bcurL);
  k_bin_all<<<501, 256, 0, stream>>>(l0e, l1e, labels, bcur0, bcur1, bcurL, tmp0, tmp1, tmpL);
  k_scan_all<<<3, 64, 0, stream>>>(bcur0, bb0, offs0+N_PTS, bcur1, bb1, offs1+M_CL, bcurL, bbL, offsL+M_CL);
  k_build_all<<<768, 256, 0, stream>>>(tmp0, bcur0, bb0, offs0, csr0,
                                       tmp1, bcur1, bb1, offs1, csr1,
                                       tmpL, bcurL, bbL, offsL, csrL);

  // ---- FUSED encoder: rel + f1 (bf16) + g0' (f16) ----
  k_f1g<<<GBG_N, 256, 0, stream>>>(features, points, centers, labels, W_fe, b_fe,
      wt+7*4096, mbe+0, mWe+0*4288, rel, UF1, gbuf, N_PTS, NT_N);

  // ---- layer0: agg -> FUSED [f2 -> UF2] + [g1' -> gbuf] ----
  k_edge_agg<<<GB_N,256,0,stream>>>(offs0, csr0, points, gbuf, mWe+0*4288, abuf, N_PTS);
  k_gemm<true,1,false,false,true,false,1,false><<<GBG_N,256,0,stream>>>(abuf, wt+0*4096, mbu+0,
      nullptr, nullptr, nullptr, UF1, nullptr, UF2,
      wt+8*4096, mbe+64, mWe+1*4288, points, gbuf, N_PTS, NT_N);
  // ---- layer1: agg -> FUSED [f2_1 -> UF21] + [h -> gbuf] ----
  k_edge_agg<<<GB_N,256,0,stream>>>(offs0, csr0, points, gbuf, mWe+1*4288, abuf, N_PTS);
  k_gemm<true,1,false,false,true,false,1,true><<<GBG_N,256,0,stream>>>(abuf, wt+1*4096, mbu+64,
      nullptr, nullptr, nullptr, UF2, nullptr, UF21,
      wt+11*4096, b_m1, W_m1+4096, rel, gbuf, N_PTS, NT_N);
  // ---- c = segsum(h); FUSED [f3 -> UF3] + [cg0' -> cg_b] ----
  k_seg_gather<<<(M_CL*64+255)/256, 256, 0, stream>>>(offsL, csrL, gbuf, cb_b, M_CL);
  k_gemm<true,0,false,false,true,false,1,false><<<GBG_M,256,0,stream>>>(cb_b, wt+4*4096, b_m2,
      nullptr, nullptr, nullptr, nullptr, nullptr, UF3,
      wt+13*4096, gbe+0, gWe+0*4288, centers, cg_b, M_CL, NT_M);
  // ---- cluster layer0: agg -> FUSED [f4 -> UF4] + [cg1' -> cg_b] ----
  k_edge_agg<<<GBG_M,256,0,stream>>>(offs1, csr1, centers, cg_b, gWe+0*4288, cagg_b, M_CL);
  k_gemm<true,1,false,false,true,false,1,false><<<GBG_M,256,0,stream>>>(cagg_b, wt+5*4096, gbu+0,
      nullptr, nullptr, nullptr, UF3, nullptr, UF4,
      wt+14*4096, gbe+64, gWe+1*4288, centers, cg_b, M_CL, NT_M);
  // ---- cluster layer1: agg -> f4_1 -> f41_b ----
  k_edge_agg<<<GBG_M,256,0,stream>>>(offs1, csr1, centers, cg_b, gWe+1*4288, cagg_b, M_CL);
  k_gemm<true,1,false,false,true,false,0,false><<<GBG_M,256,0,stream>>>(cagg_b, wt+6*4096, gbu+64,
      nullptr, nullptr, nullptr, UF4, nullptr, f41_b,
      nullptr, nullptr, nullptr, nullptr, nullptr, M_CL, NT_M);
  // ---- FUSED [f5 -> UF5] + [g2' -> gbuf] ----
  k_gemm<true,0,true,true,true,false,1,false><<<GBG_N,256,0,stream>>>(f41_b, wt+12*4096, b_l,
      W_l+4096, rel, labels, nullptr, nullptr, UF5,
      wt+9*4096, mbe+128, mWe+2*4288, points, gbuf, N_PTS, NT_N);
  // ---- layer2: agg -> FUSED [f6 = relu+f5+f2_1 -> UF6] + [g3' -> gbuf] ----
  k_edge_agg<<<GB_N,256,0,stream>>>(offs0, csr0, points, gbuf, mWe+2*4288, abuf, N_PTS);
  k_gemm<true,2,false,false,true,false,1,false><<<GBG_N,256,0,stream>>>(abuf, wt+2*4096, mbu+128,
      nullptr, nullptr, nullptr, UF5, UF21, UF6,
      wt+10*4096, mbe+192, mWe+3*4288, points, gbuf, N_PTS, NT_N);
  // ---- layer3: agg -> FUSED [final = relu+f6+f2] + [out = final@W_c + b_c] ----
  k_edge_agg<<<GB_N,256,0,stream>>>(offs0, csr0, points, gbuf, mWe+3*4288, abuf, N_PTS);
  k_gemm<true,2,false,false,false,false,2,false><<<GBG_N,256,0,stream>>>(abuf, wt+3*4096, mbu+192,
      nullptr, nullptr, nullptr, UF6, UF2, nullptr,
      wtc, b_c, nullptr, nullptr, out, N_PTS, NT_N);
}